// Round 7
// baseline (512.940 us; speedup 1.0000x reference)
//
#include <hip/hip_runtime.h>

typedef unsigned short ushort_t;
typedef __bf16 bf16x8 __attribute__((ext_vector_type(8)));
typedef float f32x4 __attribute__((ext_vector_type(4)));

#define BB 4
#define TT 2048
#define DIMD 1024
#define NH 16
#define DK 64
#define MROWS (BB * TT)   /* 8192 */
#define NQKV (3 * DIMD)   /* 3072 */

__device__ __forceinline__ ushort_t f2b(float f) {
  __bf16 h = (__bf16)f;
  union { __bf16 h; ushort_t u; } c; c.h = h; return c.u;
}

// C[m,n] = sum_k A[m,k] * W[n,k] + bias[n]
// A: [M,K] f32 (A_F32) or bf16; W: [N,K] f32 (cast to bf16 in staging);
// bias: [N] f32; C: [M,N] f32 (OUT_F32) or bf16.
template <bool A_F32, bool OUT_F32>
__global__ __launch_bounds__(256) void gemm_bt_bias(
    const void* __restrict__ Ap, const float* __restrict__ Wf,
    const float* __restrict__ bias, void* __restrict__ Cp,
    int M, int N, int K)
{
  __shared__ __align__(16) ushort_t As[128][32];
  __shared__ __align__(16) ushort_t Bs[128][32];

  const int tid = threadIdx.x;
  const int wave = tid >> 6, lane = tid & 63;
  const int tiles_n = N >> 7;
  const int bm = blockIdx.x / tiles_n, bn = blockIdx.x % tiles_n;
  const int row0 = bm << 7, col0 = bn << 7;
  const int wm = (wave >> 1) << 6;
  const int wn = (wave & 1) << 6;
  const int fr = lane & 15;
  const int fk = (lane >> 4) << 3;
  const int g4 = (lane >> 4) << 2;
  const int srow = tid >> 1;
  const int sc0  = (tid & 1) << 4;

  f32x4 acc[4][4] = {};

  for (int k0 = 0; k0 < K; k0 += 32) {
    ushort_t abuf[16], wbuf[16];
    if constexpr (A_F32) {
      const float* s = (const float*)Ap + (size_t)(row0 + srow) * K + (k0 + sc0);
#pragma unroll
      for (int q = 0; q < 4; ++q) {
        float4 f = *(const float4*)(s + q * 4);
        abuf[q * 4 + 0] = f2b(f.x); abuf[q * 4 + 1] = f2b(f.y);
        abuf[q * 4 + 2] = f2b(f.z); abuf[q * 4 + 3] = f2b(f.w);
      }
    } else {
      const ushort_t* s = (const ushort_t*)Ap + (size_t)(row0 + srow) * K + (k0 + sc0);
      *(uint4*)&abuf[0] = *(const uint4*)s;
      *(uint4*)&abuf[8] = *(const uint4*)(s + 8);
    }
    {
      const float* s = Wf + (size_t)(col0 + srow) * K + (k0 + sc0);
#pragma unroll
      for (int q = 0; q < 4; ++q) {
        float4 f = *(const float4*)(s + q * 4);
        wbuf[q * 4 + 0] = f2b(f.x); wbuf[q * 4 + 1] = f2b(f.y);
        wbuf[q * 4 + 2] = f2b(f.z); wbuf[q * 4 + 3] = f2b(f.w);
      }
    }
    __syncthreads();
    *(uint4*)&As[srow][sc0]     = *(const uint4*)&abuf[0];
    *(uint4*)&As[srow][sc0 + 8] = *(const uint4*)&abuf[8];
    *(uint4*)&Bs[srow][sc0]     = *(const uint4*)&wbuf[0];
    *(uint4*)&Bs[srow][sc0 + 8] = *(const uint4*)&wbuf[8];
    __syncthreads();

    bf16x8 af[4], bw[4];
#pragma unroll
    for (int i = 0; i < 4; ++i) {
      af[i] = *(const bf16x8*)&As[wm + (i << 4) + fr][fk];
      bw[i] = *(const bf16x8*)&Bs[wn + (i << 4) + fr][fk];
    }
#pragma unroll
    for (int mi = 0; mi < 4; ++mi)
#pragma unroll
      for (int ni = 0; ni < 4; ++ni)
        acc[mi][ni] = __builtin_amdgcn_mfma_f32_16x16x32_bf16(af[mi], bw[ni], acc[mi][ni], 0, 0, 0);
  }

#pragma unroll
  for (int ni = 0; ni < 4; ++ni) {
    const int col = col0 + wn + (ni << 4) + fr;
    const float bv = bias[col];
#pragma unroll
    for (int mi = 0; mi < 4; ++mi)
#pragma unroll
      for (int r = 0; r < 4; ++r) {
        const size_t row = (size_t)(row0 + wm + (mi << 4) + g4 + r);
        if constexpr (OUT_F32)
          ((float*)Cp)[row * (size_t)N + col] = acc[mi][ni][r] + bv;
        else
          ((ushort_t*)Cp)[row * (size_t)N + col] = f2b(acc[mi][ni][r] + bv);
      }
  }
}

// async global->LDS, 16B per lane; LDS dest is wave-uniform base + lane*16
__device__ __forceinline__ void gload_lds16(const void* g, void* l) {
  __builtin_amdgcn_global_load_lds(
      (const __attribute__((address_space(1))) void*)g,
      (__attribute__((address_space(3))) void*)l,
      16, 0, 0);
}

// Fused causal flash attention over qkv[M,3072] -> ctx[M,1024] (bf16)
__global__ __launch_bounds__(256) void attn_fused(
    const ushort_t* __restrict__ qkv, ushort_t* __restrict__ ctx)
{
  __shared__ __align__(16) ushort_t Qs[64][64];
  __shared__ __align__(16) ushort_t Ks[64][64];
  __shared__ __align__(16) ushort_t Vt[64][64];       // transposed: Vt[d][kv]
  __shared__ __align__(16) ushort_t Ps[4][16][64];    // per-wave P tile

  const int tid = threadIdx.x, wave = tid >> 6, lane = tid & 63;
  const int fr = lane & 15;
  const int fk = (lane >> 4) << 3;
  const int g4 = (lane >> 4) << 2;

  const int qt = blockIdx.x & 31;            // q tile (T/64 = 32)
  const int h  = (blockIdx.x >> 5) & 15;
  const int b  = blockIdx.x >> 9;

  const size_t qrow0 = (size_t)b * TT + (size_t)qt * 64;
  const ushort_t* Qg = qkv + qrow0 * NQKV + h * DK;

#pragma unroll
  for (int p = 0; p < 2; ++p) {
    const int lds_off = (wave << 10) + (p << 12);
    const int e  = lds_off >> 1;
    const int el = e + lane * 8;
    const int rr = el >> 6, cc = el & 63;
    gload_lds16(Qg + (size_t)rr * NQKV + cc, (ushort_t*)Qs + e);
  }

  float mrow[4] = {-1e30f, -1e30f, -1e30f, -1e30f};
  float lrow[4] = {0.f, 0.f, 0.f, 0.f};
  f32x4 oacc[4] = {};

  for (int kt = 0; kt <= qt; ++kt) {
    __syncthreads();
    const size_t krow0 = (size_t)b * TT + (size_t)kt * 64;
    const ushort_t* Kg = qkv + krow0 * NQKV + DIMD + h * DK;
    const ushort_t* Vg = qkv + krow0 * NQKV + 2 * DIMD + h * DK;

#pragma unroll
    for (int p = 0; p < 2; ++p) {
      const int lds_off = (wave << 10) + (p << 12);
      const int e  = lds_off >> 1;
      const int el = e + lane * 8;
      const int rr = el >> 6, cc = el & 63;
      gload_lds16(Kg + (size_t)rr * NQKV + cc, (ushort_t*)Ks + e);
    }
    {
      const int r  = tid >> 2;
      const int c0 = (tid & 3) << 4;
      const ushort_t* src = Vg + (size_t)r * NQKV + c0;
      ushort_t tmp[16];
      *(uint4*)&tmp[0] = *(const uint4*)&src[0];
      *(uint4*)&tmp[8] = *(const uint4*)&src[8];
#pragma unroll
      for (int j = 0; j < 16; ++j) Vt[c0 + j][r] = tmp[j];
    }
    __syncthreads();

    f32x4 s[4] = {};
#pragma unroll
    for (int ks = 0; ks < 2; ++ks) {
      const bf16x8 aq = *(const bf16x8*)&Qs[(wave << 4) + fr][(ks << 5) + fk];
#pragma unroll
      for (int ni = 0; ni < 4; ++ni) {
        const bf16x8 bk = *(const bf16x8*)&Ks[(ni << 4) + fr][(ks << 5) + fk];
        s[ni] = __builtin_amdgcn_mfma_f32_16x16x32_bf16(aq, bk, s[ni], 0, 0, 0);
      }
    }

    float p[4][4];
#pragma unroll
    for (int r = 0; r < 4; ++r) {
      const int qrow = (qt << 6) + (wave << 4) + g4 + r;
      float rm = -1e30f;
#pragma unroll
      for (int ni = 0; ni < 4; ++ni) {
        float sc = s[ni][r] * 0.125f;
        const int kc = (kt << 6) + (ni << 4) + fr;
        sc = (kc <= qrow) ? sc : -1e30f;
        p[ni][r] = sc;
        rm = fmaxf(rm, sc);
      }
#pragma unroll
      for (int off = 1; off < 16; off <<= 1)
        rm = fmaxf(rm, __shfl_xor(rm, off, 64));
      const float mn = fmaxf(mrow[r], rm);
      const float corr = __expf(mrow[r] - mn);
      mrow[r] = mn;
      float rs = 0.f;
#pragma unroll
      for (int ni = 0; ni < 4; ++ni) {
        const float pe = __expf(p[ni][r] - mn);
        p[ni][r] = pe;
        rs += pe;
      }
#pragma unroll
      for (int off = 1; off < 16; off <<= 1)
        rs += __shfl_xor(rs, off, 64);
      lrow[r] = lrow[r] * corr + rs;
#pragma unroll
      for (int ni = 0; ni < 4; ++ni) oacc[ni][r] *= corr;
    }

#pragma unroll
    for (int r = 0; r < 4; ++r)
#pragma unroll
      for (int ni = 0; ni < 4; ++ni)
        Ps[wave][g4 + r][(ni << 4) + fr] = f2b(p[ni][r]);

    asm volatile("s_waitcnt lgkmcnt(0)" ::: "memory");
    __builtin_amdgcn_sched_barrier(0);

#pragma unroll
    for (int ks = 0; ks < 2; ++ks) {
      const bf16x8 ap = *(const bf16x8*)&Ps[wave][fr][(ks << 5) + fk];
#pragma unroll
      for (int ni = 0; ni < 4; ++ni) {
        const bf16x8 bv = *(const bf16x8*)&Vt[(ni << 4) + fr][(ks << 5) + fk];
        oacc[ni] = __builtin_amdgcn_mfma_f32_16x16x32_bf16(ap, bv, oacc[ni], 0, 0, 0);
      }
    }
  }

#pragma unroll
  for (int ni = 0; ni < 4; ++ni)
#pragma unroll
    for (int r = 0; r < 4; ++r) {
      const size_t row = qrow0 + (wave << 4) + g4 + r;
      ctx[row * DIMD + h * DK + (ni << 4) + fr] = f2b(oacc[ni][r] / lrow[r]);
    }
}

__global__ __launch_bounds__(256) void copy_f32(
    const float* __restrict__ in, float* __restrict__ out, int n)
{
  const int stride = gridDim.x * blockDim.x * 4;
  for (int i = (blockIdx.x * blockDim.x + threadIdx.x) * 4; i < n; i += stride)
    *(float4*)(out + i) = *(const float4*)(in + i);
}

extern "C" void kernel_launch(void* const* d_in, const int* in_sizes, int n_in,
                              void* d_out, int out_size, void* d_ws, size_t ws_size,
                              hipStream_t stream) {
  const float* x     = (const float*)d_in[0];
  const float* w_qkv = (const float*)d_in[1];
  const float* b_qkv = (const float*)d_in[2];
  const float* w_out = (const float*)d_in[3];
  const float* b_out = (const float*)d_in[4];

  const size_t need = (size_t)MROWS * NQKV * sizeof(ushort_t);   // 48 MiB
  if (ws_size < need) return;

  ushort_t* qkv     = (ushort_t*)d_ws;   // [8192,3072] bf16 in ws
  ushort_t* ctx     = (ushort_t*)d_out;  // [8192,1024] bf16 scratch in d_out low bytes
  float*    out_tmp = (float*)d_ws;      // [8192,1024] f32, overwrites dead qkv region
  float*    out     = (float*)d_out;     // final f32 output

  // 1) QKV projection (f32 inputs cast in staging) -> bf16 qkv
  gemm_bt_bias<true, false><<<dim3((MROWS / 128) * (NQKV / 128)), dim3(256), 0, stream>>>(
      (const void*)x, w_qkv, b_qkv, (void*)qkv, MROWS, NQKV, DIMD);
  // 2) causal flash attention -> bf16 ctx (scratch inside d_out)
  attn_fused<<<dim3(BB * NH * (TT / 64)), dim3(256), 0, stream>>>(qkv, ctx);
  // 3) output projection: reads bf16 ctx, writes f32 into ws
  gemm_bt_bias<false, true><<<dim3((MROWS / 128) * (DIMD / 128)), dim3(256), 0, stream>>>(
      (const void*)ctx, w_out, b_out, (void*)out_tmp, MROWS, DIMD, DIMD);
  // 4) final f32 result -> d_out (fully overwrites the ctx scratch)
  copy_f32<<<dim3(2048), dim3(256), 0, stream>>>(out_tmp, out, MROWS * DIMD);
}

// Round 8
// 337.161 us; speedup vs baseline: 1.5213x; 1.5213x over previous
//
#include <hip/hip_runtime.h>

typedef unsigned short ushort_t;
typedef __bf16 bf16x8 __attribute__((ext_vector_type(8)));
typedef float f32x4 __attribute__((ext_vector_type(4)));

#define BB 4
#define TT 2048
#define DIMD 1024
#define NH 16
#define DK 64
#define MROWS (BB * TT)   /* 8192 */
#define NQKV (3 * DIMD)   /* 3072 */

__device__ __forceinline__ ushort_t f2b(float f) {
  __bf16 h = (__bf16)f;
  union { __bf16 h; ushort_t u; } c; c.h = h; return c.u;
}

// async global->LDS, 16B per lane; LDS dest is wave-uniform base + lane*16
__device__ __forceinline__ void gload_lds16(const void* g, void* l) {
  __builtin_amdgcn_global_load_lds(
      (const __attribute__((address_space(1))) void*)g,
      (__attribute__((address_space(3))) void*)l,
      16, 0, 0);
}

// ---------------- GEMM (unchanged from round 7, verified) ----------------
template <bool A_F32, bool OUT_F32>
__global__ __launch_bounds__(256) void gemm_bt_bias(
    const void* __restrict__ Ap, const float* __restrict__ Wf,
    const float* __restrict__ bias, void* __restrict__ Cp,
    int M, int N, int K)
{
  __shared__ __align__(16) ushort_t As[128][32];
  __shared__ __align__(16) ushort_t Bs[128][32];

  const int tid = threadIdx.x;
  const int wave = tid >> 6, lane = tid & 63;
  const int tiles_n = N >> 7;
  const int bm = blockIdx.x / tiles_n, bn = blockIdx.x % tiles_n;
  const int row0 = bm << 7, col0 = bn << 7;
  const int wm = (wave >> 1) << 6;
  const int wn = (wave & 1) << 6;
  const int fr = lane & 15;
  const int fk = (lane >> 4) << 3;
  const int g4 = (lane >> 4) << 2;
  const int srow = tid >> 1;
  const int sc0  = (tid & 1) << 4;

  f32x4 acc[4][4] = {};

  for (int k0 = 0; k0 < K; k0 += 32) {
    ushort_t abuf[16], wbuf[16];
    if constexpr (A_F32) {
      const float* s = (const float*)Ap + (size_t)(row0 + srow) * K + (k0 + sc0);
#pragma unroll
      for (int q = 0; q < 4; ++q) {
        float4 f = *(const float4*)(s + q * 4);
        abuf[q * 4 + 0] = f2b(f.x); abuf[q * 4 + 1] = f2b(f.y);
        abuf[q * 4 + 2] = f2b(f.z); abuf[q * 4 + 3] = f2b(f.w);
      }
    } else {
      const ushort_t* s = (const ushort_t*)Ap + (size_t)(row0 + srow) * K + (k0 + sc0);
      *(uint4*)&abuf[0] = *(const uint4*)s;
      *(uint4*)&abuf[8] = *(const uint4*)(s + 8);
    }
    {
      const float* s = Wf + (size_t)(col0 + srow) * K + (k0 + sc0);
#pragma unroll
      for (int q = 0; q < 4; ++q) {
        float4 f = *(const float4*)(s + q * 4);
        wbuf[q * 4 + 0] = f2b(f.x); wbuf[q * 4 + 1] = f2b(f.y);
        wbuf[q * 4 + 2] = f2b(f.z); wbuf[q * 4 + 3] = f2b(f.w);
      }
    }
    __syncthreads();
    *(uint4*)&As[srow][sc0]     = *(const uint4*)&abuf[0];
    *(uint4*)&As[srow][sc0 + 8] = *(const uint4*)&abuf[8];
    *(uint4*)&Bs[srow][sc0]     = *(const uint4*)&wbuf[0];
    *(uint4*)&Bs[srow][sc0 + 8] = *(const uint4*)&wbuf[8];
    __syncthreads();

    bf16x8 af[4], bw[4];
#pragma unroll
    for (int i = 0; i < 4; ++i) {
      af[i] = *(const bf16x8*)&As[wm + (i << 4) + fr][fk];
      bw[i] = *(const bf16x8*)&Bs[wn + (i << 4) + fr][fk];
    }
#pragma unroll
    for (int mi = 0; mi < 4; ++mi)
#pragma unroll
      for (int ni = 0; ni < 4; ++ni)
        acc[mi][ni] = __builtin_amdgcn_mfma_f32_16x16x32_bf16(af[mi], bw[ni], acc[mi][ni], 0, 0, 0);
  }

#pragma unroll
  for (int ni = 0; ni < 4; ++ni) {
    const int col = col0 + wn + (ni << 4) + fr;
    const float bv = bias[col];
#pragma unroll
    for (int mi = 0; mi < 4; ++mi)
#pragma unroll
      for (int r = 0; r < 4; ++r) {
        const size_t row = (size_t)(row0 + wm + (mi << 4) + g4 + r);
        if constexpr (OUT_F32)
          ((float*)Cp)[row * (size_t)N + col] = acc[mi][ni][r] + bv;
        else
          ((ushort_t*)Cp)[row * (size_t)N + col] = f2b(acc[mi][ni][r] + bv);
      }
  }
}

// ---------------- Flash attention: swizzled LDS + K-prefetch + tile pairing --
// qkv[M,3072] bf16 -> ctx[M,1024] bf16. Block = (b, h, bq); q-tiles {bq, 31-bq}.
__global__ __launch_bounds__(256) void attn_fused(
    const ushort_t* __restrict__ qkv, ushort_t* __restrict__ ctx)
{
  __shared__ __align__(16) ushort_t Qs[64 * 64];
  __shared__ __align__(16) ushort_t Ks[2][64 * 64];
  __shared__ __align__(16) ushort_t Vt[64 * 64];       // Vt[d][kv], hh-swizzled
  __shared__ __align__(16) ushort_t Ps[4][16 * 64];    // per-wave P, row-swizzled

  const int tid = threadIdx.x, wave = tid >> 6, lane = tid & 63;
  const int fr = lane & 15;
  const int fk = (lane >> 4) << 3;
  const int g4 = (lane >> 4) << 2;

  const int bq = blockIdx.x & 15;
  const int h  = (blockIdx.x >> 4) & 15;
  const int b  = blockIdx.x >> 8;

  // staging geometry: per gload, lane covers row (chunk + lane>>3),
  // source column pre-swizzled so linear LDS == swizzled layout (rule #21)
  const int srl = lane >> 3;
  const int scc = ((lane & 7) ^ srl) << 3;
  // V reg-staging geometry
  const int vr = tid >> 2;           // kv row 0..63
  const int vc = (tid & 3) << 4;     // d col {0,16,32,48}

  const int rsw = (fr & 7) << 3;     // read-side element XOR for Qs/Ks/Ps rows

#pragma unroll 1
  for (int t = 0; t < 2; ++t) {
    const int qt = t ? (31 - bq) : bq;
    const size_t qrow0 = (size_t)b * TT + (size_t)qt * 64;

    __syncthreads();   // prior tile fully consumed before restaging

    // stage Q, K(0); issue V(0) register loads
    const ushort_t* Qg = qkv + qrow0 * NQKV + h * DK;
    const ushort_t* Kg = qkv + (size_t)b * TT * NQKV + DIMD + h * DK;
    const ushort_t* Vg = qkv + (size_t)b * TT * NQKV + 2 * DIMD + h * DK;
#pragma unroll
    for (int p = 0; p < 2; ++p) {
      const int e  = (wave << 9) + (p << 11);
      const int rr = (e >> 6) + srl;
      gload_lds16(Qg + (size_t)rr * NQKV + scc, Qs + e);
      gload_lds16(Kg + (size_t)rr * NQKV + scc, Ks[0] + e);
    }
    uint4 va, vb;
    {
      const ushort_t* s = Vg + (size_t)vr * NQKV + vc;
      va = *(const uint4*)s;
      vb = *(const uint4*)(s + 8);
    }
    asm volatile("s_waitcnt vmcnt(0)" ::: "memory");
    __syncthreads();

    // hoist Q fragments (swizzled read)
    bf16x8 aqr[2];
#pragma unroll
    for (int ks = 0; ks < 2; ++ks)
      aqr[ks] = *(const bf16x8*)&Qs[((wave << 4) + fr) * 64 + (((ks << 5) + fk) ^ rsw)];

    float mrow[4] = {-1e30f, -1e30f, -1e30f, -1e30f};
    float lrow[4] = {0.f, 0.f, 0.f, 0.f};
    f32x4 oacc[4] = {};
    int cur = 0;

    for (int kt = 0; kt <= qt; ++kt) {
      // scatter V(kt) into Vt (hh-swizzled: ~2-way on writes AND reads)
      {
        ushort_t tmp[16];
        *(uint4*)&tmp[0] = va;
        *(uint4*)&tmp[8] = vb;
#pragma unroll
        for (int j = 0; j < 16; ++j) {
          const int d  = vc + j;
          const int hh = (d & 7) ^ ((d >> 3) & 7);
          Vt[d * 64 + (vr ^ (hh << 3))] = tmp[j];
        }
      }
      // prefetch K(kt+1) DMA + V(kt+1) regs; stays in flight across barrier B
      if (kt < qt) {
        const size_t krow = (size_t)(kt + 1) * 64;
#pragma unroll
        for (int p = 0; p < 2; ++p) {
          const int e  = (wave << 9) + (p << 11);
          const int rr = (e >> 6) + srl;
          gload_lds16(Kg + (krow + rr) * NQKV + scc, Ks[cur ^ 1] + e);
        }
        const ushort_t* s = Vg + (krow + vr) * NQKV + vc;
        va = *(const uint4*)s;
        vb = *(const uint4*)(s + 8);
      }
      asm volatile("s_waitcnt lgkmcnt(0)" ::: "memory");   // Vt writes drained
      __builtin_amdgcn_s_barrier();                        // [B] no vmcnt drain

      // S = Q K^T
      f32x4 s[4] = {};
#pragma unroll
      for (int ks = 0; ks < 2; ++ks)
#pragma unroll
        for (int ni = 0; ni < 4; ++ni) {
          const bf16x8 bk = *(const bf16x8*)&Ks[cur][((ni << 4) + fr) * 64 + (((ks << 5) + fk) ^ rsw)];
          s[ni] = __builtin_amdgcn_mfma_f32_16x16x32_bf16(aqr[ks], bk, s[ni], 0, 0, 0);
        }

      // scale + causal mask + online softmax (unchanged math)
      float p[4][4];
#pragma unroll
      for (int r = 0; r < 4; ++r) {
        const int qrow = (qt << 6) + (wave << 4) + g4 + r;
        float rm = -1e30f;
#pragma unroll
        for (int ni = 0; ni < 4; ++ni) {
          float sc = s[ni][r] * 0.125f;
          const int kc = (kt << 6) + (ni << 4) + fr;
          sc = (kc <= qrow) ? sc : -1e30f;
          p[ni][r] = sc;
          rm = fmaxf(rm, sc);
        }
#pragma unroll
        for (int off = 1; off < 16; off <<= 1)
          rm = fmaxf(rm, __shfl_xor(rm, off, 64));
        const float mn = fmaxf(mrow[r], rm);
        const float corr = __expf(mrow[r] - mn);
        mrow[r] = mn;
        float rs = 0.f;
#pragma unroll
        for (int ni = 0; ni < 4; ++ni) {
          const float pe = __expf(p[ni][r] - mn);
          p[ni][r] = pe;
          rs += pe;
        }
#pragma unroll
        for (int off = 1; off < 16; off <<= 1)
          rs += __shfl_xor(rs, off, 64);
        lrow[r] = lrow[r] * corr + rs;
#pragma unroll
        for (int ni = 0; ni < 4; ++ni) oacc[ni][r] *= corr;
      }

      // P (C-layout) -> LDS (swizzled) -> A-layout
#pragma unroll
      for (int r = 0; r < 4; ++r)
#pragma unroll
        for (int ni = 0; ni < 4; ++ni)
          Ps[wave][(g4 + r) * 64 + (((ni << 4) + fr) ^ (((g4 + r) & 7) << 3))] = f2b(p[ni][r]);

      asm volatile("s_waitcnt lgkmcnt(0)" ::: "memory");
      __builtin_amdgcn_sched_barrier(0);

      // O += P V
#pragma unroll
      for (int ks = 0; ks < 2; ++ks) {
        const bf16x8 ap = *(const bf16x8*)&Ps[wave][fr * 64 + (((ks << 5) + fk) ^ rsw)];
#pragma unroll
        for (int ni = 0; ni < 4; ++ni) {
          const int hh = (fr & 7) ^ ((2 * ni + (fr >> 3)) & 7);
          const bf16x8 bv = *(const bf16x8*)&Vt[((ni << 4) + fr) * 64 + (((ks << 5) + fk) ^ (hh << 3))];
          oacc[ni] = __builtin_amdgcn_mfma_f32_16x16x32_bf16(ap, bv, oacc[ni], 0, 0, 0);
        }
      }

      if (kt < qt) {
        asm volatile("s_waitcnt vmcnt(0)" ::: "memory");   // [A] drain prefetches
        __syncthreads();                                   // everyone done with Vt/Ks
      }
      cur ^= 1;
    }

    // epilogue: O / l -> ctx
#pragma unroll
    for (int ni = 0; ni < 4; ++ni)
#pragma unroll
      for (int r = 0; r < 4; ++r) {
        const size_t row = qrow0 + (wave << 4) + g4 + r;
        ctx[row * DIMD + h * DK + (ni << 4) + fr] = f2b(oacc[ni][r] / lrow[r]);
      }
  }
}

__global__ __launch_bounds__(256) void copy_f32(
    const float* __restrict__ in, float* __restrict__ out, int n)
{
  const int stride = gridDim.x * blockDim.x * 4;
  for (int i = (blockIdx.x * blockDim.x + threadIdx.x) * 4; i < n; i += stride)
    *(float4*)(out + i) = *(const float4*)(in + i);
}

extern "C" void kernel_launch(void* const* d_in, const int* in_sizes, int n_in,
                              void* d_out, int out_size, void* d_ws, size_t ws_size,
                              hipStream_t stream) {
  const float* x     = (const float*)d_in[0];
  const float* w_qkv = (const float*)d_in[1];
  const float* b_qkv = (const float*)d_in[2];
  const float* w_out = (const float*)d_in[3];
  const float* b_out = (const float*)d_in[4];

  const size_t need = (size_t)MROWS * NQKV * sizeof(ushort_t);   // 48 MiB
  if (ws_size < need) return;

  ushort_t* qkv     = (ushort_t*)d_ws;   // [8192,3072] bf16 in ws
  ushort_t* ctx     = (ushort_t*)d_out;  // [8192,1024] bf16 scratch in d_out low bytes
  float*    out_tmp = (float*)d_ws;      // [8192,1024] f32, overwrites dead qkv region
  float*    out     = (float*)d_out;     // final f32 output

  gemm_bt_bias<true, false><<<dim3((MROWS / 128) * (NQKV / 128)), dim3(256), 0, stream>>>(
      (const void*)x, w_qkv, b_qkv, (void*)qkv, MROWS, NQKV, DIMD);
  attn_fused<<<dim3(BB * NH * 16), dim3(256), 0, stream>>>(qkv, ctx);
  gemm_bt_bias<false, true><<<dim3((MROWS / 128) * (DIMD / 128)), dim3(256), 0, stream>>>(
      (const void*)ctx, w_out, b_out, (void*)out_tmp, MROWS, DIMD, DIMD);
  copy_f32<<<dim3(2048), dim3(256), 0, stream>>>(out_tmp, out, MROWS * DIMD);
}

// Round 9
// 254.193 us; speedup vs baseline: 2.0179x; 1.3264x over previous
//
#include <hip/hip_runtime.h>

typedef unsigned short ushort_t;
typedef __bf16 bf16x8 __attribute__((ext_vector_type(8)));
typedef float f32x4 __attribute__((ext_vector_type(4)));

#define BB 4
#define TT 2048
#define DIMD 1024
#define NH 16
#define DK 64
#define MROWS (BB * TT)   /* 8192 */
#define NQKV (3 * DIMD)   /* 3072 */

__device__ __forceinline__ ushort_t f2b(float f) {
  __bf16 h = (__bf16)f;
  union { __bf16 h; ushort_t u; } c; c.h = h; return c.u;
}

// async global->LDS, 16B per lane; LDS dest is wave-uniform base + lane*16
__device__ __forceinline__ void gload_lds16(const void* g, void* l) {
  __builtin_amdgcn_global_load_lds(
      (const __attribute__((address_space(1))) void*)g,
      (__attribute__((address_space(3))) void*)l,
      16, 0, 0);
}

// ---------------- GEMM (unchanged, verified) ----------------
template <bool A_F32, bool OUT_F32>
__global__ __launch_bounds__(256) void gemm_bt_bias(
    const void* __restrict__ Ap, const float* __restrict__ Wf,
    const float* __restrict__ bias, void* __restrict__ Cp,
    int M, int N, int K)
{
  __shared__ __align__(16) ushort_t As[128][32];
  __shared__ __align__(16) ushort_t Bs[128][32];

  const int tid = threadIdx.x;
  const int wave = tid >> 6, lane = tid & 63;
  const int tiles_n = N >> 7;
  const int bm = blockIdx.x / tiles_n, bn = blockIdx.x % tiles_n;
  const int row0 = bm << 7, col0 = bn << 7;
  const int wm = (wave >> 1) << 6;
  const int wn = (wave & 1) << 6;
  const int fr = lane & 15;
  const int fk = (lane >> 4) << 3;
  const int g4 = (lane >> 4) << 2;
  const int srow = tid >> 1;
  const int sc0  = (tid & 1) << 4;

  f32x4 acc[4][4] = {};

  for (int k0 = 0; k0 < K; k0 += 32) {
    ushort_t abuf[16], wbuf[16];
    if constexpr (A_F32) {
      const float* s = (const float*)Ap + (size_t)(row0 + srow) * K + (k0 + sc0);
#pragma unroll
      for (int q = 0; q < 4; ++q) {
        float4 f = *(const float4*)(s + q * 4);
        abuf[q * 4 + 0] = f2b(f.x); abuf[q * 4 + 1] = f2b(f.y);
        abuf[q * 4 + 2] = f2b(f.z); abuf[q * 4 + 3] = f2b(f.w);
      }
    } else {
      const ushort_t* s = (const ushort_t*)Ap + (size_t)(row0 + srow) * K + (k0 + sc0);
      *(uint4*)&abuf[0] = *(const uint4*)s;
      *(uint4*)&abuf[8] = *(const uint4*)(s + 8);
    }
    {
      const float* s = Wf + (size_t)(col0 + srow) * K + (k0 + sc0);
#pragma unroll
      for (int q = 0; q < 4; ++q) {
        float4 f = *(const float4*)(s + q * 4);
        wbuf[q * 4 + 0] = f2b(f.x); wbuf[q * 4 + 1] = f2b(f.y);
        wbuf[q * 4 + 2] = f2b(f.z); wbuf[q * 4 + 3] = f2b(f.w);
      }
    }
    __syncthreads();
    *(uint4*)&As[srow][sc0]     = *(const uint4*)&abuf[0];
    *(uint4*)&As[srow][sc0 + 8] = *(const uint4*)&abuf[8];
    *(uint4*)&Bs[srow][sc0]     = *(const uint4*)&wbuf[0];
    *(uint4*)&Bs[srow][sc0 + 8] = *(const uint4*)&wbuf[8];
    __syncthreads();

    bf16x8 af[4], bw[4];
#pragma unroll
    for (int i = 0; i < 4; ++i) {
      af[i] = *(const bf16x8*)&As[wm + (i << 4) + fr][fk];
      bw[i] = *(const bf16x8*)&Bs[wn + (i << 4) + fr][fk];
    }
#pragma unroll
    for (int mi = 0; mi < 4; ++mi)
#pragma unroll
      for (int ni = 0; ni < 4; ++ni)
        acc[mi][ni] = __builtin_amdgcn_mfma_f32_16x16x32_bf16(af[mi], bw[ni], acc[mi][ni], 0, 0, 0);
  }

#pragma unroll
  for (int ni = 0; ni < 4; ++ni) {
    const int col = col0 + wn + (ni << 4) + fr;
    const float bv = bias[col];
#pragma unroll
    for (int mi = 0; mi < 4; ++mi)
#pragma unroll
      for (int r = 0; r < 4; ++r) {
        const size_t row = (size_t)(row0 + wm + (mi << 4) + g4 + r);
        if constexpr (OUT_F32)
          ((float*)Cp)[row * (size_t)N + col] = acc[mi][ni][r] + bv;
        else
          ((ushort_t*)Cp)[row * (size_t)N + col] = f2b(acc[mi][ni][r] + bv);
      }
  }
}

// ---------------- Flash attention: swapped MFMA, lane-local softmax ----------
// qkv[M,3072] bf16 -> ctx[M,1024] bf16. 512 thr / 8 waves; q-tile = 128 rows;
// block handles q-tiles {bq, 15-bq}; XCD-swizzled decode keeps one (b,h)'s
// 8 blocks on one XCD L2.
__global__ __launch_bounds__(512, 4) void attn_fused(
    const ushort_t* __restrict__ qkv, ushort_t* __restrict__ ctx)
{
  __shared__ __align__(16) ushort_t Qs[128 * 64];
  __shared__ __align__(16) ushort_t Ks[2][64 * 64];
  __shared__ __align__(16) ushort_t Vt[64 * 64];       // Vt[d][kv], hh-swizzled
  __shared__ __align__(16) ushort_t Ps[8][16 * 64];    // per-wave P, row-swizzled

  const int tid = threadIdx.x, wave = tid >> 6, lane = tid & 63;
  const int fr = lane & 15;
  const int g  = lane >> 4;
  const int fk = g << 3;
  const int g4 = g << 2;

  // XCD-swizzled decode: blocks with same (b,h) share bid%8 (same XCD)
  const int bid = blockIdx.x;
  const int bq  = (bid >> 3) & 7;
  const int G   = (bid & 7) | ((bid >> 6) << 3);
  const int h   = G & 15;
  const int b   = G >> 4;

  const int srl = lane >> 3;
  const int scc = ((lane & 7) ^ srl) << 3;   // pre-swizzled source column
  const int vr  = tid >> 3;                  // V row 0..63
  const int vc  = (tid & 7) << 3;            // V col base
  const int rsw = (fr & 7) << 3;             // read-side element XOR

  const ushort_t* Kg = qkv + (size_t)b * TT * NQKV + DIMD + h * DK;
  const ushort_t* Vg = qkv + (size_t)b * TT * NQKV + 2 * DIMD + h * DK;

#pragma unroll 1
  for (int t = 0; t < 2; ++t) {
    const int qt = t ? (15 - bq) : bq;
    const int ktmax = 2 * qt + 1;
    const size_t qrow0 = (size_t)b * TT + (size_t)qt * 128;

    __syncthreads();   // prior tile fully consumed

    const ushort_t* Qg = qkv + qrow0 * NQKV + h * DK;
#pragma unroll
    for (int pp = 0; pp < 2; ++pp) {
      const int e  = (wave << 9) + (pp << 12);   // elements
      const int rr = (e >> 6) + srl;
      gload_lds16(Qg + (size_t)rr * NQKV + scc, Qs + e);
    }
    {
      const int e  = wave << 9;
      const int rr = (wave << 3) + srl;
      gload_lds16(Kg + (size_t)rr * NQKV + scc, Ks[0] + e);
    }
    uint4 va = *(const uint4*)(Vg + (size_t)vr * NQKV + vc);
    asm volatile("s_waitcnt vmcnt(0)" ::: "memory");
    __syncthreads();

    // hoist Q fragments (B-operand layout: row = q = wave*16+fr)
    bf16x8 aqr[2];
#pragma unroll
    for (int ks = 0; ks < 2; ++ks)
      aqr[ks] = *(const bf16x8*)&Qs[((wave << 4) + fr) * 64 + (((ks << 5) + fk) ^ rsw)];

    const int qrow = (qt << 7) + (wave << 4) + fr;   // lane-local q row
    float mrow = -1e30f, lrow = 0.f;
    f32x4 oacc[4] = {};   // [ni][r]: O[q=qrow][d = ni*16 + g4 + r]
    int cur = 0;

    for (int kt = 0; kt <= ktmax; ++kt) {
      // scatter V(kt) regs -> Vt (hh-swizzled, ~2-way banks)
      {
        __align__(16) ushort_t tmp[8];
        *(uint4*)tmp = va;
#pragma unroll
        for (int j = 0; j < 8; ++j) {
          const int d  = vc + j;
          const int hh = (d & 7) ^ ((d >> 3) & 7);
          Vt[d * 64 + (vr ^ (hh << 3))] = tmp[j];
        }
      }
      // prefetch K(kt+1) DMA + V(kt+1) regs; stay in flight across barrier
      if (kt < ktmax) {
        const size_t krow = (size_t)(kt + 1) << 6;
        const int e  = wave << 9;
        const int rr = (wave << 3) + srl;
        gload_lds16(Kg + (krow + rr) * NQKV + scc, Ks[cur ^ 1] + e);
        va = *(const uint4*)(Vg + (krow + vr) * NQKV + vc);
      }
      asm volatile("s_waitcnt lgkmcnt(0)" ::: "memory");   // Vt writes drained
      __builtin_amdgcn_s_barrier();                        // no vmcnt drain

      // S^T = mfma(K, Q): lane holds S[q=qrow][k = kt*64 + ni*16 + g4 + r]
      f32x4 s[4] = {};
#pragma unroll
      for (int ks = 0; ks < 2; ++ks)
#pragma unroll
        for (int ni = 0; ni < 4; ++ni) {
          const bf16x8 bk = *(const bf16x8*)&Ks[cur][((ni << 4) + fr) * 64 + (((ks << 5) + fk) ^ rsw)];
          s[ni] = __builtin_amdgcn_mfma_f32_16x16x32_bf16(bk, aqr[ks], s[ni], 0, 0, 0);
        }

      // causal mask (raw units; 1/8 scale folded into exp arg)
      const int kb = kt << 6;
#pragma unroll
      for (int ni = 0; ni < 4; ++ni)
#pragma unroll
        for (int r = 0; r < 4; ++r) {
          const int kc = kb + (ni << 4) + g4 + r;
          if (kc > qrow) s[ni][r] = -1e30f;
        }

      // lane-local online softmax
      float rm = -1e30f;
#pragma unroll
      for (int ni = 0; ni < 4; ++ni) {
        const float m01 = fmaxf(s[ni][0], s[ni][1]);
        const float m23 = fmaxf(s[ni][2], s[ni][3]);
        rm = fmaxf(rm, fmaxf(m01, m23));
      }
      rm = fmaxf(rm, __shfl_xor(rm, 16, 64));
      rm = fmaxf(rm, __shfl_xor(rm, 32, 64));

      if (__any(rm > mrow + 64.f)) {     // defer-max: THR = 8 (scaled) = 64 raw
        const float mn = fmaxf(mrow, rm);
        const float corr = __expf((mrow - mn) * 0.125f);
        mrow = mn;
        lrow *= corr;
#pragma unroll
        for (int ni = 0; ni < 4; ++ni) oacc[ni] *= corr;
      }
      const float nm = -mrow * 0.125f;
      float rs = 0.f;
#pragma unroll
      for (int ni = 0; ni < 4; ++ni)
#pragma unroll
        for (int r = 0; r < 4; ++r) {
          const float pe = __expf(fmaf(s[ni][r], 0.125f, nm));
          s[ni][r] = pe;
          rs += pe;
        }
      rs += __shfl_xor(rs, 16, 64);
      rs += __shfl_xor(rs, 32, 64);
      lrow += rs;

      // P -> Ps (packed b64 per ni; row = q = fr, swizzled)
#pragma unroll
      for (int ni = 0; ni < 4; ++ni) {
        ushort_t o4[4];
#pragma unroll
        for (int r = 0; r < 4; ++r) o4[r] = f2b(s[ni][r]);
        *(uint2*)&Ps[wave][fr * 64 + (((ni << 4) + g4) ^ rsw)] = *(const uint2*)o4;
      }
      asm volatile("s_waitcnt lgkmcnt(0)" ::: "memory");
      __builtin_amdgcn_sched_barrier(0);

      // O^T = mfma(Vt, P): accumulate O[q=qrow][d]
#pragma unroll
      for (int ks = 0; ks < 2; ++ks) {
        const bf16x8 ap = *(const bf16x8*)&Ps[wave][fr * 64 + (((ks << 5) + fk) ^ rsw)];
#pragma unroll
        for (int ni = 0; ni < 4; ++ni) {
          const int hh = (fr & 7) ^ ((2 * ni + (fr >> 3)) & 7);
          const bf16x8 bv = *(const bf16x8*)&Vt[((ni << 4) + fr) * 64 + (((ks << 5) + fk) ^ (hh << 3))];
          oacc[ni] = __builtin_amdgcn_mfma_f32_16x16x32_bf16(bv, ap, oacc[ni], 0, 0, 0);
        }
      }

      if (kt < ktmax) {
        asm volatile("s_waitcnt vmcnt(0)" ::: "memory");   // drain prefetches
        __syncthreads();                                   // all done with Vt/Ks
      }
      cur ^= 1;
    }

    // epilogue: O / l -> ctx (lane-local l; 4x 8B stores)
    const float inv = 1.f / lrow;
    ushort_t* crow = ctx + (qrow0 + (wave << 4) + fr) * DIMD + h * DK;
#pragma unroll
    for (int ni = 0; ni < 4; ++ni) {
      ushort_t o4[4];
#pragma unroll
      for (int r = 0; r < 4; ++r) o4[r] = f2b(oacc[ni][r] * inv);
      *(uint2*)&crow[(ni << 4) + g4] = *(const uint2*)o4;
    }
  }
}

__global__ __launch_bounds__(256) void copy_f32(
    const float* __restrict__ in, float* __restrict__ out, int n)
{
  const int stride = gridDim.x * blockDim.x * 4;
  for (int i = (blockIdx.x * blockDim.x + threadIdx.x) * 4; i < n; i += stride)
    *(float4*)(out + i) = *(const float4*)(in + i);
}

extern "C" void kernel_launch(void* const* d_in, const int* in_sizes, int n_in,
                              void* d_out, int out_size, void* d_ws, size_t ws_size,
                              hipStream_t stream) {
  const float* x     = (const float*)d_in[0];
  const float* w_qkv = (const float*)d_in[1];
  const float* b_qkv = (const float*)d_in[2];
  const float* w_out = (const float*)d_in[3];
  const float* b_out = (const float*)d_in[4];

  const size_t need = (size_t)MROWS * NQKV * sizeof(ushort_t);   // 48 MiB
  if (ws_size < need) return;

  ushort_t* qkv     = (ushort_t*)d_ws;   // [8192,3072] bf16 in ws
  ushort_t* ctx     = (ushort_t*)d_out;  // [8192,1024] bf16 scratch in d_out low bytes
  float*    out_tmp = (float*)d_ws;      // [8192,1024] f32, overwrites dead qkv region
  float*    out     = (float*)d_out;     // final f32 output

  gemm_bt_bias<true, false><<<dim3((MROWS / 128) * (NQKV / 128)), dim3(256), 0, stream>>>(
      (const void*)x, w_qkv, b_qkv, (void*)qkv, MROWS, NQKV, DIMD);
  attn_fused<<<dim3(BB * NH * 8), dim3(512), 0, stream>>>(qkv, ctx);
  gemm_bt_bias<false, true><<<dim3((MROWS / 128) * (DIMD / 128)), dim3(256), 0, stream>>>(
      (const void*)ctx, w_out, b_out, (void*)out_tmp, MROWS, DIMD, DIMD);
  copy_f32<<<dim3(2048), dim3(256), 0, stream>>>(out_tmp, out, MROWS * DIMD);
}

// Round 10
// 202.907 us; speedup vs baseline: 2.5280x; 1.2528x over previous
//
#include <hip/hip_runtime.h>

typedef unsigned short ushort_t;
typedef __bf16 bf16x8 __attribute__((ext_vector_type(8)));
typedef float f32x4 __attribute__((ext_vector_type(4)));

#define BB 4
#define TT 2048
#define DIMD 1024
#define NH 16
#define DK 64
#define MROWS (BB * TT)   /* 8192 */
#define NQKV (3 * DIMD)   /* 3072 */

__device__ __forceinline__ ushort_t f2b(float f) {
  __bf16 h = (__bf16)f;
  union { __bf16 h; ushort_t u; } c; c.h = h; return c.u;
}

// async global->LDS, 16B per lane; LDS dest is wave-uniform base + lane*16
__device__ __forceinline__ void gload_lds16(const void* g, void* l) {
  __builtin_amdgcn_global_load_lds(
      (const __attribute__((address_space(1))) void*)g,
      (__attribute__((address_space(3))) void*)l,
      16, 0, 0);
}

// f32 -> bf16 downcast, 8 elems/thread (n % 2048 == 0)
__global__ __launch_bounds__(256) void cast_f32_bf16(
    const float* __restrict__ in, ushort_t* __restrict__ out, int n)
{
  const int i = (blockIdx.x * 256 + threadIdx.x) * 8;
  if (i >= n) return;
  float4 a = *(const float4*)(in + i);
  float4 b = *(const float4*)(in + i + 4);
  ushort_t o[8];
  o[0] = f2b(a.x); o[1] = f2b(a.y); o[2] = f2b(a.z); o[3] = f2b(a.w);
  o[4] = f2b(b.x); o[5] = f2b(b.y); o[6] = f2b(b.z); o[7] = f2b(b.w);
  *(uint4*)(out + i) = *(const uint4*)o;
}

// ---------------- GEMM: bf16 operands, gload_lds staging, swizzled LDS ------
// C[m,n] = sum_k A[m,k] * W[n,k] + bias[n]
// A: [M,K] bf16; W: [N,K] bf16; bias: [N] f32; C: [M,N] f32 or bf16.
template <bool OUT_F32>
__global__ __launch_bounds__(256) void gemm_bt_bias(
    const ushort_t* __restrict__ A, const ushort_t* __restrict__ W,
    const float* __restrict__ bias, void* __restrict__ Cp,
    int M, int N, int K)
{
  __shared__ __align__(16) ushort_t As[128 * 32];
  __shared__ __align__(16) ushort_t Bs[128 * 32];

  const int tid = threadIdx.x;
  const int wave = tid >> 6, lane = tid & 63;
  const int tiles_n = N >> 7;
  const int bm = blockIdx.x / tiles_n, bn = blockIdx.x % tiles_n;
  const int row0 = bm << 7, col0 = bn << 7;
  const int wm = (wave >> 1) << 6;
  const int wn = (wave & 1) << 6;
  const int fr = lane & 15;
  const int fk = (lane >> 4) << 3;
  const int g4 = (lane >> 4) << 2;

  // staging: lane covers 8 elems of row (base + lane>>2), col (lane&3)*8,
  // source column XOR-swizzled so linear LDS dest == swizzled layout
  const int sr = lane >> 2;                                 // row sub-offset
  // fragment-read swizzle: col ^= ((row>>1)&3)<<3, row parity from fr
  const int csw = fk ^ (((fr >> 1) & 3) << 3);

  f32x4 acc[4][4] = {};

  for (int k0 = 0; k0 < K; k0 += 32) {
    __syncthreads();   // previous tile consumed
#pragma unroll
    for (int p = 0; p < 2; ++p) {
      const int e = (wave << 9) + (p << 11);                // element base
      const int r = (e >> 5) + sr;                          // tile row
      const int c = ((lane & 3) << 3) ^ (((r >> 1) & 3) << 3);
      gload_lds16(A + (size_t)(row0 + r) * K + (k0 + c), As + e);
      gload_lds16(W + (size_t)(col0 + r) * K + (k0 + c), Bs + e);
    }
    __syncthreads();   // compiler drains vmcnt(0) before s_barrier

    bf16x8 af[4], bw[4];
#pragma unroll
    for (int i = 0; i < 4; ++i) {
      af[i] = *(const bf16x8*)&As[(wm + (i << 4) + fr) * 32 + csw];
      bw[i] = *(const bf16x8*)&Bs[(wn + (i << 4) + fr) * 32 + csw];
    }
#pragma unroll
    for (int mi = 0; mi < 4; ++mi)
#pragma unroll
      for (int ni = 0; ni < 4; ++ni)
        acc[mi][ni] = __builtin_amdgcn_mfma_f32_16x16x32_bf16(af[mi], bw[ni], acc[mi][ni], 0, 0, 0);
  }

#pragma unroll
  for (int ni = 0; ni < 4; ++ni) {
    const int col = col0 + wn + (ni << 4) + fr;
    const float bv = bias[col];
#pragma unroll
    for (int mi = 0; mi < 4; ++mi)
#pragma unroll
      for (int r = 0; r < 4; ++r) {
        const size_t row = (size_t)(row0 + wm + (mi << 4) + g4 + r);
        if constexpr (OUT_F32)
          ((float*)Cp)[row * (size_t)N + col] = acc[mi][ni][r] + bv;
        else
          ((ushort_t*)Cp)[row * (size_t)N + col] = f2b(acc[mi][ni][r] + bv);
      }
  }
}

// ---------------- Flash attention (byte-identical to round 9) ----------------
__global__ __launch_bounds__(512, 4) void attn_fused(
    const ushort_t* __restrict__ qkv, ushort_t* __restrict__ ctx)
{
  __shared__ __align__(16) ushort_t Qs[128 * 64];
  __shared__ __align__(16) ushort_t Ks[2][64 * 64];
  __shared__ __align__(16) ushort_t Vt[64 * 64];       // Vt[d][kv], hh-swizzled
  __shared__ __align__(16) ushort_t Ps[8][16 * 64];    // per-wave P, row-swizzled

  const int tid = threadIdx.x, wave = tid >> 6, lane = tid & 63;
  const int fr = lane & 15;
  const int g  = lane >> 4;
  const int fk = g << 3;
  const int g4 = g << 2;

  const int bid = blockIdx.x;
  const int bq  = (bid >> 3) & 7;
  const int G   = (bid & 7) | ((bid >> 6) << 3);
  const int h   = G & 15;
  const int b   = G >> 4;

  const int srl = lane >> 3;
  const int scc = ((lane & 7) ^ srl) << 3;
  const int vr  = tid >> 3;
  const int vc  = (tid & 7) << 3;
  const int rsw = (fr & 7) << 3;

  const ushort_t* Kg = qkv + (size_t)b * TT * NQKV + DIMD + h * DK;
  const ushort_t* Vg = qkv + (size_t)b * TT * NQKV + 2 * DIMD + h * DK;

#pragma unroll 1
  for (int t = 0; t < 2; ++t) {
    const int qt = t ? (15 - bq) : bq;
    const int ktmax = 2 * qt + 1;
    const size_t qrow0 = (size_t)b * TT + (size_t)qt * 128;

    __syncthreads();

    const ushort_t* Qg = qkv + qrow0 * NQKV + h * DK;
#pragma unroll
    for (int pp = 0; pp < 2; ++pp) {
      const int e  = (wave << 9) + (pp << 12);
      const int rr = (e >> 6) + srl;
      gload_lds16(Qg + (size_t)rr * NQKV + scc, Qs + e);
    }
    {
      const int e  = wave << 9;
      const int rr = (wave << 3) + srl;
      gload_lds16(Kg + (size_t)rr * NQKV + scc, Ks[0] + e);
    }
    uint4 va = *(const uint4*)(Vg + (size_t)vr * NQKV + vc);
    asm volatile("s_waitcnt vmcnt(0)" ::: "memory");
    __syncthreads();

    bf16x8 aqr[2];
#pragma unroll
    for (int ks = 0; ks < 2; ++ks)
      aqr[ks] = *(const bf16x8*)&Qs[((wave << 4) + fr) * 64 + (((ks << 5) + fk) ^ rsw)];

    const int qrow = (qt << 7) + (wave << 4) + fr;
    float mrow = -1e30f, lrow = 0.f;
    f32x4 oacc[4] = {};
    int cur = 0;

    for (int kt = 0; kt <= ktmax; ++kt) {
      {
        __align__(16) ushort_t tmp[8];
        *(uint4*)tmp = va;
#pragma unroll
        for (int j = 0; j < 8; ++j) {
          const int d  = vc + j;
          const int hh = (d & 7) ^ ((d >> 3) & 7);
          Vt[d * 64 + (vr ^ (hh << 3))] = tmp[j];
        }
      }
      if (kt < ktmax) {
        const size_t krow = (size_t)(kt + 1) << 6;
        const int e  = wave << 9;
        const int rr = (wave << 3) + srl;
        gload_lds16(Kg + (krow + rr) * NQKV + scc, Ks[cur ^ 1] + e);
        va = *(const uint4*)(Vg + (krow + vr) * NQKV + vc);
      }
      asm volatile("s_waitcnt lgkmcnt(0)" ::: "memory");
      __builtin_amdgcn_s_barrier();

      f32x4 s[4] = {};
#pragma unroll
      for (int ks = 0; ks < 2; ++ks)
#pragma unroll
        for (int ni = 0; ni < 4; ++ni) {
          const bf16x8 bk = *(const bf16x8*)&Ks[cur][((ni << 4) + fr) * 64 + (((ks << 5) + fk) ^ rsw)];
          s[ni] = __builtin_amdgcn_mfma_f32_16x16x32_bf16(bk, aqr[ks], s[ni], 0, 0, 0);
        }

      const int kb = kt << 6;
#pragma unroll
      for (int ni = 0; ni < 4; ++ni)
#pragma unroll
        for (int r = 0; r < 4; ++r) {
          const int kc = kb + (ni << 4) + g4 + r;
          if (kc > qrow) s[ni][r] = -1e30f;
        }

      float rm = -1e30f;
#pragma unroll
      for (int ni = 0; ni < 4; ++ni) {
        const float m01 = fmaxf(s[ni][0], s[ni][1]);
        const float m23 = fmaxf(s[ni][2], s[ni][3]);
        rm = fmaxf(rm, fmaxf(m01, m23));
      }
      rm = fmaxf(rm, __shfl_xor(rm, 16, 64));
      rm = fmaxf(rm, __shfl_xor(rm, 32, 64));

      if (__any(rm > mrow + 64.f)) {
        const float mn = fmaxf(mrow, rm);
        const float corr = __expf((mrow - mn) * 0.125f);
        mrow = mn;
        lrow *= corr;
#pragma unroll
        for (int ni = 0; ni < 4; ++ni) oacc[ni] *= corr;
      }
      const float nm = -mrow * 0.125f;
      float rs = 0.f;
#pragma unroll
      for (int ni = 0; ni < 4; ++ni)
#pragma unroll
        for (int r = 0; r < 4; ++r) {
          const float pe = __expf(fmaf(s[ni][r], 0.125f, nm));
          s[ni][r] = pe;
          rs += pe;
        }
      rs += __shfl_xor(rs, 16, 64);
      rs += __shfl_xor(rs, 32, 64);
      lrow += rs;

#pragma unroll
      for (int ni = 0; ni < 4; ++ni) {
        ushort_t o4[4];
#pragma unroll
        for (int r = 0; r < 4; ++r) o4[r] = f2b(s[ni][r]);
        *(uint2*)&Ps[wave][fr * 64 + (((ni << 4) + g4) ^ rsw)] = *(const uint2*)o4;
      }
      asm volatile("s_waitcnt lgkmcnt(0)" ::: "memory");
      __builtin_amdgcn_sched_barrier(0);

#pragma unroll
      for (int ks = 0; ks < 2; ++ks) {
        const bf16x8 ap = *(const bf16x8*)&Ps[wave][fr * 64 + (((ks << 5) + fk) ^ rsw)];
#pragma unroll
        for (int ni = 0; ni < 4; ++ni) {
          const int hh = (fr & 7) ^ ((2 * ni + (fr >> 3)) & 7);
          const bf16x8 bv = *(const bf16x8*)&Vt[((ni << 4) + fr) * 64 + (((ks << 5) + fk) ^ (hh << 3))];
          oacc[ni] = __builtin_amdgcn_mfma_f32_16x16x32_bf16(bv, ap, oacc[ni], 0, 0, 0);
        }
      }

      if (kt < ktmax) {
        asm volatile("s_waitcnt vmcnt(0)" ::: "memory");
        __syncthreads();
      }
      cur ^= 1;
    }

    const float inv = 1.f / lrow;
    ushort_t* crow = ctx + (qrow0 + (wave << 4) + fr) * DIMD + h * DK;
#pragma unroll
    for (int ni = 0; ni < 4; ++ni) {
      ushort_t o4[4];
#pragma unroll
      for (int r = 0; r < 4; ++r) o4[r] = f2b(oacc[ni][r] * inv);
      *(uint2*)&crow[(ni << 4) + g4] = *(const uint2*)o4;
    }
  }
}

__global__ __launch_bounds__(256) void copy_f32(
    const float* __restrict__ in, float* __restrict__ out, int n)
{
  const int stride = gridDim.x * blockDim.x * 4;
  for (int i = (blockIdx.x * blockDim.x + threadIdx.x) * 4; i < n; i += stride)
    *(float4*)(out + i) = *(const float4*)(in + i);
}

extern "C" void kernel_launch(void* const* d_in, const int* in_sizes, int n_in,
                              void* d_out, int out_size, void* d_ws, size_t ws_size,
                              hipStream_t stream) {
  const float* x     = (const float*)d_in[0];
  const float* w_qkv = (const float*)d_in[1];
  const float* b_qkv = (const float*)d_in[2];
  const float* w_out = (const float*)d_in[3];
  const float* b_out = (const float*)d_in[4];

  const size_t need = (size_t)MROWS * NQKV * sizeof(ushort_t);   // 48 MiB
  if (ws_size < need) return;

  // d_out (32 MiB) doubles as staging scratch; all lifetimes disjoint:
  //   xb  [0,16MiB)  : bf16 x       — dead after gemm1
  //   wqb [16,22MiB) : bf16 w_qkv   — dead after gemm1
  //   wob [22,24MiB) : bf16 w_out   — dead after gemm3
  //   ctx [0,16MiB)  : bf16 context — written by attn (xb dead), read by gemm3
  //   final copy overwrites all 32 MiB with f32 result
  ushort_t* dsc  = (ushort_t*)d_out;
  ushort_t* xb   = dsc;                                  // 8 Mi elems
  ushort_t* wqb  = dsc + (size_t)MROWS * DIMD;           // 3 Mi elems
  ushort_t* wob  = wqb + (size_t)NQKV * DIMD;            // 1 Mi elems
  ushort_t* ctx  = dsc;

  ushort_t* qkv     = (ushort_t*)d_ws;   // [8192,3072] bf16
  float*    out_tmp = (float*)d_ws;      // f32 result, overwrites dead qkv
  float*    out     = (float*)d_out;

  // 0) precast inputs to bf16
  cast_f32_bf16<<<dim3(MROWS * DIMD / 2048), dim3(256), 0, stream>>>(x, xb, MROWS * DIMD);
  cast_f32_bf16<<<dim3(NQKV * DIMD / 2048), dim3(256), 0, stream>>>(w_qkv, wqb, NQKV * DIMD);
  cast_f32_bf16<<<dim3(DIMD * DIMD / 2048), dim3(256), 0, stream>>>(w_out, wob, DIMD * DIMD);
  // 1) QKV projection
  gemm_bt_bias<false><<<dim3((MROWS / 128) * (NQKV / 128)), dim3(256), 0, stream>>>(
      xb, wqb, b_qkv, (void*)qkv, MROWS, NQKV, DIMD);
  // 2) causal flash attention -> ctx (overwrites xb region)
  attn_fused<<<dim3(BB * NH * 8), dim3(512), 0, stream>>>(qkv, ctx);
  // 3) output projection -> f32 in ws
  gemm_bt_bias<true><<<dim3((MROWS / 128) * (DIMD / 128)), dim3(256), 0, stream>>>(
      ctx, wob, b_out, (void*)out_tmp, MROWS, DIMD, DIMD);
  // 4) final f32 result -> d_out
  copy_f32<<<dim3(2048), dim3(256), 0, stream>>>(out_tmp, out, MROWS * DIMD);
}

// Round 11
// 184.488 us; speedup vs baseline: 2.7803x; 1.0998x over previous
//
#include <hip/hip_runtime.h>

typedef unsigned short ushort_t;
typedef __bf16 bf16x8 __attribute__((ext_vector_type(8)));
typedef float f32x4 __attribute__((ext_vector_type(4)));

#define BB 4
#define TT 2048
#define DIMD 1024
#define NH 16
#define DK 64
#define MROWS (BB * TT)   /* 8192 */
#define NQKV (3 * DIMD)   /* 3072 */

__device__ __forceinline__ ushort_t f2b(float f) {
  __bf16 h = (__bf16)f;
  union { __bf16 h; ushort_t u; } c; c.h = h; return c.u;
}
__device__ __forceinline__ float fexp2(float x) {   // v_exp_f32: 2^x
  float r;
  asm("v_exp_f32 %0, %1" : "=v"(r) : "v"(x));
  return r;
}

// async global->LDS, 16B per lane; LDS dest is wave-uniform base + lane*16
__device__ __forceinline__ void gload_lds16(const void* g, void* l) {
  __builtin_amdgcn_global_load_lds(
      (const __attribute__((address_space(1))) void*)g,
      (__attribute__((address_space(3))) void*)l,
      16, 0, 0);
}

// f32 -> bf16 downcast, 8 elems/thread (n % 2048 == 0)
__global__ __launch_bounds__(256) void cast_f32_bf16(
    const float* __restrict__ in, ushort_t* __restrict__ out, int n)
{
  const int i = (blockIdx.x * 256 + threadIdx.x) * 8;
  if (i >= n) return;
  float4 a = *(const float4*)(in + i);
  float4 b = *(const float4*)(in + i + 4);
  ushort_t o[8];
  o[0] = f2b(a.x); o[1] = f2b(a.y); o[2] = f2b(a.z); o[3] = f2b(a.w);
  o[4] = f2b(b.x); o[5] = f2b(b.y); o[6] = f2b(b.z); o[7] = f2b(b.w);
  *(uint4*)(out + i) = *(const uint4*)o;
}

// ---------------- GEMM: bf16 operands, gload_lds staging, swizzled LDS ------
// C[m,n] = sum_k A[m,k] * W[n,k] + bias[n]
template <bool OUT_F32>
__global__ __launch_bounds__(256) void gemm_bt_bias(
    const ushort_t* __restrict__ A, const ushort_t* __restrict__ W,
    const float* __restrict__ bias, void* __restrict__ Cp,
    int M, int N, int K)
{
  __shared__ __align__(16) ushort_t As[128 * 32];
  __shared__ __align__(16) ushort_t Bs[128 * 32];

  const int tid = threadIdx.x;
  const int wave = tid >> 6, lane = tid & 63;
  const int tiles_n = N >> 7;
  const int bm = blockIdx.x / tiles_n, bn = blockIdx.x % tiles_n;
  const int row0 = bm << 7, col0 = bn << 7;
  const int wm = (wave >> 1) << 6;
  const int wn = (wave & 1) << 6;
  const int fr = lane & 15;
  const int fk = (lane >> 4) << 3;
  const int g4 = (lane >> 4) << 2;

  const int sr = lane >> 2;                                 // staging row sub-offset
  const int csw = fk ^ (((fr >> 1) & 3) << 3);              // fragment-read swizzle

  f32x4 acc[4][4] = {};

  for (int k0 = 0; k0 < K; k0 += 32) {
    __syncthreads();
#pragma unroll
    for (int p = 0; p < 2; ++p) {
      const int e = (wave << 9) + (p << 11);
      const int r = (e >> 5) + sr;
      const int c = ((lane & 3) << 3) ^ (((r >> 1) & 3) << 3);
      gload_lds16(A + (size_t)(row0 + r) * K + (k0 + c), As + e);
      gload_lds16(W + (size_t)(col0 + r) * K + (k0 + c), Bs + e);
    }
    __syncthreads();

    bf16x8 af[4], bw[4];
#pragma unroll
    for (int i = 0; i < 4; ++i) {
      af[i] = *(const bf16x8*)&As[(wm + (i << 4) + fr) * 32 + csw];
      bw[i] = *(const bf16x8*)&Bs[(wn + (i << 4) + fr) * 32 + csw];
    }
#pragma unroll
    for (int mi = 0; mi < 4; ++mi)
#pragma unroll
      for (int ni = 0; ni < 4; ++ni)
        acc[mi][ni] = __builtin_amdgcn_mfma_f32_16x16x32_bf16(af[mi], bw[ni], acc[mi][ni], 0, 0, 0);
  }

#pragma unroll
  for (int ni = 0; ni < 4; ++ni) {
    const int col = col0 + wn + (ni << 4) + fr;
    const float bv = bias[col];
#pragma unroll
    for (int mi = 0; mi < 4; ++mi)
#pragma unroll
      for (int r = 0; r < 4; ++r) {
        const size_t row = (size_t)(row0 + wm + (mi << 4) + g4 + r);
        if constexpr (OUT_F32)
          ((float*)Cp)[row * (size_t)N + col] = acc[mi][ni][r] + bv;
        else
          ((ushort_t*)Cp)[row * (size_t)N + col] = f2b(acc[mi][ni][r] + bv);
      }
  }
}

// ---------------- Flash attention: loop-split mask, exp2 softmax, setprio ---
#define C1 0.18033688011112042f   /* 0.125 * log2(e) */
__global__ __launch_bounds__(512, 4) void attn_fused(
    const ushort_t* __restrict__ qkv, ushort_t* __restrict__ ctx)
{
  __shared__ __align__(16) ushort_t Qs[128 * 64];
  __shared__ __align__(16) ushort_t Ks[2][64 * 64];
  __shared__ __align__(16) ushort_t Vt[64 * 64];       // Vt[d][kv], hh-swizzled
  __shared__ __align__(16) ushort_t Ps[8][16 * 64];    // per-wave P, row-swizzled

  const int tid = threadIdx.x, wave = tid >> 6, lane = tid & 63;
  const int fr = lane & 15;
  const int g  = lane >> 4;
  const int fk = g << 3;
  const int g4 = g << 2;

  const int bid = blockIdx.x;
  const int bq  = (bid >> 3) & 7;
  const int G   = (bid & 7) | ((bid >> 6) << 3);
  const int h   = G & 15;
  const int b   = G >> 4;

  const int srl = lane >> 3;
  const int scc = ((lane & 7) ^ srl) << 3;
  const int vr  = tid >> 3;
  const int vc  = (tid & 7) << 3;
  const int rsw = (fr & 7) << 3;

  const ushort_t* Kg = qkv + (size_t)b * TT * NQKV + DIMD + h * DK;
  const ushort_t* Vg = qkv + (size_t)b * TT * NQKV + 2 * DIMD + h * DK;

#pragma unroll 1
  for (int t = 0; t < 2; ++t) {
    const int qt = t ? (15 - bq) : bq;
    const int ktmax = 2 * qt + 1;
    const int diag  = 2 * qt + (wave >> 2);    // wave-uniform diagonal k-tile
    const size_t qrow0 = (size_t)b * TT + (size_t)qt * 128;

    __syncthreads();

    const ushort_t* Qg = qkv + qrow0 * NQKV + h * DK;
#pragma unroll
    for (int pp = 0; pp < 2; ++pp) {
      const int e  = (wave << 9) + (pp << 12);
      const int rr = (e >> 6) + srl;
      gload_lds16(Qg + (size_t)rr * NQKV + scc, Qs + e);
    }
    {
      const int e  = wave << 9;
      const int rr = (wave << 3) + srl;
      gload_lds16(Kg + (size_t)rr * NQKV + scc, Ks[0] + e);
    }
    uint4 va = *(const uint4*)(Vg + (size_t)vr * NQKV + vc);
    asm volatile("s_waitcnt vmcnt(0)" ::: "memory");
    __syncthreads();

    bf16x8 aqr[2];
#pragma unroll
    for (int ks = 0; ks < 2; ++ks)
      aqr[ks] = *(const bf16x8*)&Qs[((wave << 4) + fr) * 64 + (((ks << 5) + fk) ^ rsw)];

    const int qrow = (qt << 7) + (wave << 4) + fr;
    float mrow = -1e30f, lrow = 0.f;
    f32x4 oacc[4] = {};
    int cur = 0;

    for (int kt = 0; kt <= ktmax; ++kt) {
      {  // cooperative V scatter (all waves, every step)
        __align__(16) ushort_t tmp[8];
        *(uint4*)tmp = va;
#pragma unroll
        for (int j = 0; j < 8; ++j) {
          const int d  = vc + j;
          const int hh = (d & 7) ^ ((d >> 3) & 7);
          Vt[d * 64 + (vr ^ (hh << 3))] = tmp[j];
        }
      }
      if (kt < ktmax) {   // cooperative prefetch
        const size_t krow = (size_t)(kt + 1) << 6;
        const int e  = wave << 9;
        const int rr = (wave << 3) + srl;
        gload_lds16(Kg + (krow + rr) * NQKV + scc, Ks[cur ^ 1] + e);
        va = *(const uint4*)(Vg + (krow + vr) * NQKV + vc);
      }
      asm volatile("s_waitcnt lgkmcnt(0)" ::: "memory");
      __builtin_amdgcn_s_barrier();

      if (kt <= diag) {   // wave-uniform: skip fully-masked step
        f32x4 s[4] = {};
        __builtin_amdgcn_s_setprio(1);
#pragma unroll
        for (int ks = 0; ks < 2; ++ks)
#pragma unroll
          for (int ni = 0; ni < 4; ++ni) {
            const bf16x8 bk = *(const bf16x8*)&Ks[cur][((ni << 4) + fr) * 64 + (((ks << 5) + fk) ^ rsw)];
            s[ni] = __builtin_amdgcn_mfma_f32_16x16x32_bf16(bk, aqr[ks], s[ni], 0, 0, 0);
          }
        __builtin_amdgcn_s_setprio(0);

        if (kt == diag) {   // mask only the diagonal tile
          const int kb = kt << 6;
#pragma unroll
          for (int ni = 0; ni < 4; ++ni)
#pragma unroll
            for (int r = 0; r < 4; ++r) {
              const int kc = kb + (ni << 4) + g4 + r;
              if (kc > qrow) s[ni][r] = -1e30f;
            }
        }

        float rm = -1e30f;
#pragma unroll
        for (int ni = 0; ni < 4; ++ni) {
          const float m01 = fmaxf(s[ni][0], s[ni][1]);
          const float m23 = fmaxf(s[ni][2], s[ni][3]);
          rm = fmaxf(rm, fmaxf(m01, m23));
        }
        rm = fmaxf(rm, __shfl_xor(rm, 16, 64));
        rm = fmaxf(rm, __shfl_xor(rm, 32, 64));

        if (__any(rm > mrow + 64.f)) {   // defer-max (THR = 8 scaled = 64 raw)
          const float mn = fmaxf(mrow, rm);
          const float corr = fexp2((mrow - mn) * C1);
          mrow = mn;
          lrow *= corr;
#pragma unroll
          for (int ni = 0; ni < 4; ++ni) oacc[ni] *= corr;
        }
        const float nm2 = -mrow * C1;
        float rs = 0.f;
#pragma unroll
        for (int ni = 0; ni < 4; ++ni)
#pragma unroll
          for (int r = 0; r < 4; ++r) {
            const float pe = fexp2(fmaf(s[ni][r], C1, nm2));
            s[ni][r] = pe;
            rs += pe;
          }
        rs += __shfl_xor(rs, 16, 64);
        rs += __shfl_xor(rs, 32, 64);
        lrow += rs;

#pragma unroll
        for (int ni = 0; ni < 4; ++ni) {
          ushort_t o4[4];
#pragma unroll
          for (int r = 0; r < 4; ++r) o4[r] = f2b(s[ni][r]);
          *(uint2*)&Ps[wave][fr * 64 + (((ni << 4) + g4) ^ rsw)] = *(const uint2*)o4;
        }
        asm volatile("s_waitcnt lgkmcnt(0)" ::: "memory");
        __builtin_amdgcn_sched_barrier(0);

        __builtin_amdgcn_s_setprio(1);
#pragma unroll
        for (int ks = 0; ks < 2; ++ks) {
          const bf16x8 ap = *(const bf16x8*)&Ps[wave][fr * 64 + (((ks << 5) + fk) ^ rsw)];
#pragma unroll
          for (int ni = 0; ni < 4; ++ni) {
            const int hh = (fr & 7) ^ ((2 * ni + (fr >> 3)) & 7);
            const bf16x8 bv = *(const bf16x8*)&Vt[((ni << 4) + fr) * 64 + (((ks << 5) + fk) ^ (hh << 3))];
            oacc[ni] = __builtin_amdgcn_mfma_f32_16x16x32_bf16(bv, ap, oacc[ni], 0, 0, 0);
          }
        }
        __builtin_amdgcn_s_setprio(0);
      }

      if (kt < ktmax) {
        asm volatile("s_waitcnt vmcnt(0)" ::: "memory");
        __syncthreads();
      }
      cur ^= 1;
    }

    const float inv = 1.f / lrow;
    ushort_t* crow = ctx + (qrow0 + (wave << 4) + fr) * DIMD + h * DK;
#pragma unroll
    for (int ni = 0; ni < 4; ++ni) {
      ushort_t o4[4];
#pragma unroll
      for (int r = 0; r < 4; ++r) o4[r] = f2b(oacc[ni][r] * inv);
      *(uint2*)&crow[(ni << 4) + g4] = *(const uint2*)o4;
    }
  }
}

extern "C" void kernel_launch(void* const* d_in, const int* in_sizes, int n_in,
                              void* d_out, int out_size, void* d_ws, size_t ws_size,
                              hipStream_t stream) {
  const float* x     = (const float*)d_in[0];
  const float* w_qkv = (const float*)d_in[1];
  const float* b_qkv = (const float*)d_in[2];
  const float* w_out = (const float*)d_in[3];
  const float* b_out = (const float*)d_in[4];

  // ws layout (bf16 elems): qkv[0,24Mi) | xb[24Mi,32Mi) | wqb[32Mi,35Mi) | wob[35Mi,36Mi)
  // ctx reuses xb (dead after gemm1). Total 72 MiB; rounds 2-5 bit-identical
  // results prove ws >= ~92 MB (writes at 88+ MiB landed intact).
  const size_t need = 36u * 1024 * 1024 * sizeof(ushort_t);   // 72 MiB
  if (ws_size < need) return;

  ushort_t* qkv = (ushort_t*)d_ws;
  ushort_t* xb  = qkv + (size_t)MROWS * NQKV;
  ushort_t* wqb = xb  + (size_t)MROWS * DIMD;
  ushort_t* wob = wqb + (size_t)NQKV * DIMD;
  ushort_t* ctx = xb;
  float*    out = (float*)d_out;

  cast_f32_bf16<<<dim3(MROWS * DIMD / 2048), dim3(256), 0, stream>>>(x, xb, MROWS * DIMD);
  cast_f32_bf16<<<dim3(NQKV * DIMD / 2048), dim3(256), 0, stream>>>(w_qkv, wqb, NQKV * DIMD);
  cast_f32_bf16<<<dim3(DIMD * DIMD / 2048), dim3(256), 0, stream>>>(w_out, wob, DIMD * DIMD);
  gemm_bt_bias<false><<<dim3((MROWS / 128) * (NQKV / 128)), dim3(256), 0, stream>>>(
      xb, wqb, b_qkv, (void*)qkv, MROWS, NQKV, DIMD);
  attn_fused<<<dim3(BB * NH * 8), dim3(512), 0, stream>>>(qkv, ctx);
  gemm_bt_bias<true><<<dim3((MROWS / 128) * (DIMD / 128)), dim3(256), 0, stream>>>(
      ctx, wob, b_out, (void*)out, MROWS, DIMD, DIMD);
}

// Round 12
// 183.129 us; speedup vs baseline: 2.8010x; 1.0074x over previous
//
#include <hip/hip_runtime.h>

typedef unsigned short ushort_t;
typedef __bf16 bf16x8 __attribute__((ext_vector_type(8)));
typedef float f32x4 __attribute__((ext_vector_type(4)));

#define BB 4
#define TT 2048
#define DIMD 1024
#define NH 16
#define DK 64
#define MROWS (BB * TT)   /* 8192 */
#define NQKV (3 * DIMD)   /* 3072 */

__device__ __forceinline__ ushort_t f2b(float f) {
  __bf16 h = (__bf16)f;
  union { __bf16 h; ushort_t u; } c; c.h = h; return c.u;
}
__device__ __forceinline__ float fexp2(float x) {   // v_exp_f32: 2^x
  float r;
  asm("v_exp_f32 %0, %1" : "=v"(r) : "v"(x));
  return r;
}

// async global->LDS, 16B per lane; LDS dest is wave-uniform base + lane*16
__device__ __forceinline__ void gload_lds16(const void* g, void* l) {
  __builtin_amdgcn_global_load_lds(
      (const __attribute__((address_space(1))) void*)g,
      (__attribute__((address_space(3))) void*)l,
      16, 0, 0);
}

// f32 -> bf16 downcast, 8 elems/thread (n % 2048 == 0)
__global__ __launch_bounds__(256) void cast_f32_bf16(
    const float* __restrict__ in, ushort_t* __restrict__ out, int n)
{
  const int i = (blockIdx.x * 256 + threadIdx.x) * 8;
  if (i >= n) return;
  float4 a = *(const float4*)(in + i);
  float4 b = *(const float4*)(in + i + 4);
  ushort_t o[8];
  o[0] = f2b(a.x); o[1] = f2b(a.y); o[2] = f2b(a.z); o[3] = f2b(a.w);
  o[4] = f2b(b.x); o[5] = f2b(b.y); o[6] = f2b(b.z); o[7] = f2b(b.w);
  *(uint4*)(out + i) = *(const uint4*)o;
}

// ---------------- GEMM 256x256: 8-wave, dbuf LDS, counted-vmcnt pipeline ----
// C[m,n] = sum_k A[m,k]*W[n,k] + bias[n]. M%256==0, N%256==0, K%64==0, K>=128.
// Schedule per K-tile t (slot t&1):
//   vmcnt(8)        -> tile t fully in LDS (only tile t+1's 8 loads outstanding)
//   s_barrier       -> all waves' DMA for tile t drained
//   ds_read 24xb128 (frags, XOR-swizzled); lgkmcnt(0)
//   s_barrier       -> ALL waves done reading slot t&1
//   issue stage(t+2) into slot t&1   (WAR-safe; stays in flight across barriers)
//   setprio(1); 64x MFMA; setprio(0)
template <bool OUT_F32>
__global__ __launch_bounds__(512, 2) void gemm_bt_bias_256(
    const ushort_t* __restrict__ A, const ushort_t* __restrict__ W,
    const float* __restrict__ bias, void* __restrict__ Cp,
    int M, int N, int K)
{
  __shared__ __align__(16) ushort_t As[2][256 * 64];
  __shared__ __align__(16) ushort_t Bs[2][256 * 64];

  const int tid = threadIdx.x;
  const int wave = tid >> 6, lane = tid & 63;
  const int tiles_n = N >> 8;
  const int nwg = (M >> 8) * tiles_n;
  int bid = blockIdx.x;
  { const int q = nwg >> 3; bid = (bid & 7) * q + (bid >> 3); }   // XCD swizzle (nwg%8==0)
  const int bm = bid / tiles_n, bn = bid % tiles_n;
  const int row0 = bm << 8, col0 = bn << 8;
  const int wm = (wave >> 2) << 7;   // 0 / 128
  const int wn = (wave & 3) << 6;    // 0,64,128,192
  const int fr = lane & 15;
  const int g  = lane >> 4;
  const int g4 = g << 2;
  const int fk = g << 3;
  const int rsw = (fr & 7) << 3;

  // staging: quarter p covers rows p*64..p*64+63; thread -> row tid>>3,
  // source col pre-swizzled so linear LDS dest == swizzled layout
  const int str = tid >> 3;
  const int stc = ((tid & 7) ^ (str & 7)) << 3;

  const ushort_t* Ab = A + (size_t)row0 * K;
  const ushort_t* Wb = W + (size_t)col0 * K;

#define STAGE256(t)                                                           \
  {                                                                           \
    const int _buf = (t) & 1;                                                 \
    const size_t _k0 = (size_t)(t) << 6;                                      \
    _Pragma("unroll")                                                         \
    for (int p = 0; p < 4; ++p) {                                             \
      const int e = (p << 12) + (wave << 9);                                  \
      const int r = (p << 6) + str;                                           \
      gload_lds16(Ab + (size_t)r * K + _k0 + stc, &As[_buf][e]);              \
      gload_lds16(Wb + (size_t)r * K + _k0 + stc, &Bs[_buf][e]);              \
    }                                                                         \
  }

  const int NT = K >> 6;
  STAGE256(0);
  STAGE256(1);

  f32x4 acc[8][4] = {};

  for (int t = 0; t < NT; ++t) {
    if (t < NT - 1) asm volatile("s_waitcnt vmcnt(8)" ::: "memory");
    else            asm volatile("s_waitcnt vmcnt(0)" ::: "memory");
    __builtin_amdgcn_s_barrier();

    const int buf = t & 1;
    bf16x8 af[8][2], bw[4][2];
#pragma unroll
    for (int i = 0; i < 8; ++i)
#pragma unroll
      for (int s = 0; s < 2; ++s)
        af[i][s] = *(const bf16x8*)&As[buf][(wm + (i << 4) + fr) * 64 + (((s << 5) + fk) ^ rsw)];
#pragma unroll
    for (int j = 0; j < 4; ++j)
#pragma unroll
      for (int s = 0; s < 2; ++s)
        bw[j][s] = *(const bf16x8*)&Bs[buf][(wn + (j << 4) + fr) * 64 + (((s << 5) + fk) ^ rsw)];
    asm volatile("s_waitcnt lgkmcnt(0)" ::: "memory");
    __builtin_amdgcn_s_barrier();

    if (t + 2 < NT) STAGE256(t + 2);

    __builtin_amdgcn_s_setprio(1);
#pragma unroll
    for (int s = 0; s < 2; ++s)
#pragma unroll
      for (int i = 0; i < 8; ++i)
#pragma unroll
        for (int j = 0; j < 4; ++j)
          acc[i][j] = __builtin_amdgcn_mfma_f32_16x16x32_bf16(af[i][s], bw[j][s], acc[i][j], 0, 0, 0);
    __builtin_amdgcn_s_setprio(0);
  }
#undef STAGE256

#pragma unroll
  for (int j = 0; j < 4; ++j) {
    const int col = col0 + wn + (j << 4) + fr;
    const float bv = bias[col];
#pragma unroll
    for (int i = 0; i < 8; ++i)
#pragma unroll
      for (int r = 0; r < 4; ++r) {
        const size_t row = (size_t)(row0 + wm + (i << 4) + g4 + r);
        if constexpr (OUT_F32)
          ((float*)Cp)[row * (size_t)N + col] = acc[i][j][r] + bv;
        else
          ((ushort_t*)Cp)[row * (size_t)N + col] = f2b(acc[i][j][r] + bv);
      }
  }
}

// ---------------- GEMM 128x128 (round-11 verified; used for out-proj) -------
template <bool OUT_F32>
__global__ __launch_bounds__(256) void gemm_bt_bias(
    const ushort_t* __restrict__ A, const ushort_t* __restrict__ W,
    const float* __restrict__ bias, void* __restrict__ Cp,
    int M, int N, int K)
{
  __shared__ __align__(16) ushort_t As[128 * 32];
  __shared__ __align__(16) ushort_t Bs[128 * 32];

  const int tid = threadIdx.x;
  const int wave = tid >> 6, lane = tid & 63;
  const int tiles_n = N >> 7;
  const int bm = blockIdx.x / tiles_n, bn = blockIdx.x % tiles_n;
  const int row0 = bm << 7, col0 = bn << 7;
  const int wm = (wave >> 1) << 6;
  const int wn = (wave & 1) << 6;
  const int fr = lane & 15;
  const int fk = (lane >> 4) << 3;
  const int g4 = (lane >> 4) << 2;

  const int sr = lane >> 2;
  const int csw = fk ^ (((fr >> 1) & 3) << 3);

  f32x4 acc[4][4] = {};

  for (int k0 = 0; k0 < K; k0 += 32) {
    __syncthreads();
#pragma unroll
    for (int p = 0; p < 2; ++p) {
      const int e = (wave << 9) + (p << 11);
      const int r = (e >> 5) + sr;
      const int c = ((lane & 3) << 3) ^ (((r >> 1) & 3) << 3);
      gload_lds16(A + (size_t)(row0 + r) * K + (k0 + c), As + e);
      gload_lds16(W + (size_t)(col0 + r) * K + (k0 + c), Bs + e);
    }
    __syncthreads();

    bf16x8 af[4], bw[4];
#pragma unroll
    for (int i = 0; i < 4; ++i) {
      af[i] = *(const bf16x8*)&As[(wm + (i << 4) + fr) * 32 + csw];
      bw[i] = *(const bf16x8*)&Bs[(wn + (i << 4) + fr) * 32 + csw];
    }
#pragma unroll
    for (int mi = 0; mi < 4; ++mi)
#pragma unroll
      for (int ni = 0; ni < 4; ++ni)
        acc[mi][ni] = __builtin_amdgcn_mfma_f32_16x16x32_bf16(af[mi], bw[ni], acc[mi][ni], 0, 0, 0);
  }

#pragma unroll
  for (int ni = 0; ni < 4; ++ni) {
    const int col = col0 + wn + (ni << 4) + fr;
    const float bv = bias[col];
#pragma unroll
    for (int mi = 0; mi < 4; ++mi)
#pragma unroll
      for (int r = 0; r < 4; ++r) {
        const size_t row = (size_t)(row0 + wm + (mi << 4) + g4 + r);
        if constexpr (OUT_F32)
          ((float*)Cp)[row * (size_t)N + col] = acc[mi][ni][r] + bv;
        else
          ((ushort_t*)Cp)[row * (size_t)N + col] = f2b(acc[mi][ni][r] + bv);
      }
  }
}

// ---------------- Flash attention (byte-identical to round 11) --------------
#define C1 0.18033688011112042f   /* 0.125 * log2(e) */
__global__ __launch_bounds__(512, 4) void attn_fused(
    const ushort_t* __restrict__ qkv, ushort_t* __restrict__ ctx)
{
  __shared__ __align__(16) ushort_t Qs[128 * 64];
  __shared__ __align__(16) ushort_t Ks[2][64 * 64];
  __shared__ __align__(16) ushort_t Vt[64 * 64];
  __shared__ __align__(16) ushort_t Ps[8][16 * 64];

  const int tid = threadIdx.x, wave = tid >> 6, lane = tid & 63;
  const int fr = lane & 15;
  const int g  = lane >> 4;
  const int fk = g << 3;
  const int g4 = g << 2;

  const int bid = blockIdx.x;
  const int bq  = (bid >> 3) & 7;
  const int G   = (bid & 7) | ((bid >> 6) << 3);
  const int h   = G & 15;
  const int b   = G >> 4;

  const int srl = lane >> 3;
  const int scc = ((lane & 7) ^ srl) << 3;
  const int vr  = tid >> 3;
  const int vc  = (tid & 7) << 3;
  const int rsw = (fr & 7) << 3;

  const ushort_t* Kg = qkv + (size_t)b * TT * NQKV + DIMD + h * DK;
  const ushort_t* Vg = qkv + (size_t)b * TT * NQKV + 2 * DIMD + h * DK;

#pragma unroll 1
  for (int t = 0; t < 2; ++t) {
    const int qt = t ? (15 - bq) : bq;
    const int ktmax = 2 * qt + 1;
    const int diag  = 2 * qt + (wave >> 2);
    const size_t qrow0 = (size_t)b * TT + (size_t)qt * 128;

    __syncthreads();

    const ushort_t* Qg = qkv + qrow0 * NQKV + h * DK;
#pragma unroll
    for (int pp = 0; pp < 2; ++pp) {
      const int e  = (wave << 9) + (pp << 12);
      const int rr = (e >> 6) + srl;
      gload_lds16(Qg + (size_t)rr * NQKV + scc, Qs + e);
    }
    {
      const int e  = wave << 9;
      const int rr = (wave << 3) + srl;
      gload_lds16(Kg + (size_t)rr * NQKV + scc, Ks[0] + e);
    }
    uint4 va = *(const uint4*)(Vg + (size_t)vr * NQKV + vc);
    asm volatile("s_waitcnt vmcnt(0)" ::: "memory");
    __syncthreads();

    bf16x8 aqr[2];
#pragma unroll
    for (int ks = 0; ks < 2; ++ks)
      aqr[ks] = *(const bf16x8*)&Qs[((wave << 4) + fr) * 64 + (((ks << 5) + fk) ^ rsw)];

    const int qrow = (qt << 7) + (wave << 4) + fr;
    float mrow = -1e30f, lrow = 0.f;
    f32x4 oacc[4] = {};
    int cur = 0;

    for (int kt = 0; kt <= ktmax; ++kt) {
      {
        __align__(16) ushort_t tmp[8];
        *(uint4*)tmp = va;
#pragma unroll
        for (int j = 0; j < 8; ++j) {
          const int d  = vc + j;
          const int hh = (d & 7) ^ ((d >> 3) & 7);
          Vt[d * 64 + (vr ^ (hh << 3))] = tmp[j];
        }
      }
      if (kt < ktmax) {
        const size_t krow = (size_t)(kt + 1) << 6;
        const int e  = wave << 9;
        const int rr = (wave << 3) + srl;
        gload_lds16(Kg + (krow + rr) * NQKV + scc, Ks[cur ^ 1] + e);
        va = *(const uint4*)(Vg + (krow + vr) * NQKV + vc);
      }
      asm volatile("s_waitcnt lgkmcnt(0)" ::: "memory");
      __builtin_amdgcn_s_barrier();

      if (kt <= diag) {
        f32x4 s[4] = {};
        __builtin_amdgcn_s_setprio(1);
#pragma unroll
        for (int ks = 0; ks < 2; ++ks)
#pragma unroll
          for (int ni = 0; ni < 4; ++ni) {
            const bf16x8 bk = *(const bf16x8*)&Ks[cur][((ni << 4) + fr) * 64 + (((ks << 5) + fk) ^ rsw)];
            s[ni] = __builtin_amdgcn_mfma_f32_16x16x32_bf16(bk, aqr[ks], s[ni], 0, 0, 0);
          }
        __builtin_amdgcn_s_setprio(0);

        if (kt == diag) {
          const int kb = kt << 6;
#pragma unroll
          for (int ni = 0; ni < 4; ++ni)
#pragma unroll
            for (int r = 0; r < 4; ++r) {
              const int kc = kb + (ni << 4) + g4 + r;
              if (kc > qrow) s[ni][r] = -1e30f;
            }
        }

        float rm = -1e30f;
#pragma unroll
        for (int ni = 0; ni < 4; ++ni) {
          const float m01 = fmaxf(s[ni][0], s[ni][1]);
          const float m23 = fmaxf(s[ni][2], s[ni][3]);
          rm = fmaxf(rm, fmaxf(m01, m23));
        }
        rm = fmaxf(rm, __shfl_xor(rm, 16, 64));
        rm = fmaxf(rm, __shfl_xor(rm, 32, 64));

        if (__any(rm > mrow + 64.f)) {
          const float mn = fmaxf(mrow, rm);
          const float corr = fexp2((mrow - mn) * C1);
          mrow = mn;
          lrow *= corr;
#pragma unroll
          for (int ni = 0; ni < 4; ++ni) oacc[ni] *= corr;
        }
        const float nm2 = -mrow * C1;
        float rs = 0.f;
#pragma unroll
        for (int ni = 0; ni < 4; ++ni)
#pragma unroll
          for (int r = 0; r < 4; ++r) {
            const float pe = fexp2(fmaf(s[ni][r], C1, nm2));
            s[ni][r] = pe;
            rs += pe;
          }
        rs += __shfl_xor(rs, 16, 64);
        rs += __shfl_xor(rs, 32, 64);
        lrow += rs;

#pragma unroll
        for (int ni = 0; ni < 4; ++ni) {
          ushort_t o4[4];
#pragma unroll
          for (int r = 0; r < 4; ++r) o4[r] = f2b(s[ni][r]);
          *(uint2*)&Ps[wave][fr * 64 + (((ni << 4) + g4) ^ rsw)] = *(const uint2*)o4;
        }
        asm volatile("s_waitcnt lgkmcnt(0)" ::: "memory");
        __builtin_amdgcn_sched_barrier(0);

        __builtin_amdgcn_s_setprio(1);
#pragma unroll
        for (int ks = 0; ks < 2; ++ks) {
          const bf16x8 ap = *(const bf16x8*)&Ps[wave][fr * 64 + (((ks << 5) + fk) ^ rsw)];
#pragma unroll
          for (int ni = 0; ni < 4; ++ni) {
            const int hh = (fr & 7) ^ ((2 * ni + (fr >> 3)) & 7);
            const bf16x8 bv = *(const bf16x8*)&Vt[((ni << 4) + fr) * 64 + (((ks << 5) + fk) ^ (hh << 3))];
            oacc[ni] = __builtin_amdgcn_mfma_f32_16x16x32_bf16(bv, ap, oacc[ni], 0, 0, 0);
          }
        }
        __builtin_amdgcn_s_setprio(0);
      }

      if (kt < ktmax) {
        asm volatile("s_waitcnt vmcnt(0)" ::: "memory");
        __syncthreads();
      }
      cur ^= 1;
    }

    const float inv = 1.f / lrow;
    ushort_t* crow = ctx + (qrow0 + (wave << 4) + fr) * DIMD + h * DK;
#pragma unroll
    for (int ni = 0; ni < 4; ++ni) {
      ushort_t o4[4];
#pragma unroll
      for (int r = 0; r < 4; ++r) o4[r] = f2b(oacc[ni][r] * inv);
      *(uint2*)&crow[(ni << 4) + g4] = *(const uint2*)o4;
    }
  }
}

extern "C" void kernel_launch(void* const* d_in, const int* in_sizes, int n_in,
                              void* d_out, int out_size, void* d_ws, size_t ws_size,
                              hipStream_t stream) {
  const float* x     = (const float*)d_in[0];
  const float* w_qkv = (const float*)d_in[1];
  const float* b_qkv = (const float*)d_in[2];
  const float* w_out = (const float*)d_in[3];
  const float* b_out = (const float*)d_in[4];

  const size_t need = 36u * 1024 * 1024 * sizeof(ushort_t);   // 72 MiB
  if (ws_size < need) return;

  ushort_t* qkv = (ushort_t*)d_ws;
  ushort_t* xb  = qkv + (size_t)MROWS * NQKV;
  ushort_t* wqb = xb  + (size_t)MROWS * DIMD;
  ushort_t* wob = wqb + (size_t)NQKV * DIMD;
  ushort_t* ctx = xb;
  float*    out = (float*)d_out;

  cast_f32_bf16<<<dim3(MROWS * DIMD / 2048), dim3(256), 0, stream>>>(x, xb, MROWS * DIMD);
  cast_f32_bf16<<<dim3(NQKV * DIMD / 2048), dim3(256), 0, stream>>>(w_qkv, wqb, NQKV * DIMD);
  cast_f32_bf16<<<dim3(DIMD * DIMD / 2048), dim3(256), 0, stream>>>(w_out, wob, DIMD * DIMD);
  // 1) QKV projection — 256x256 pipelined GEMM (grid 384, 512 thr)
  gemm_bt_bias_256<false><<<dim3((MROWS / 256) * (NQKV / 256)), dim3(512), 0, stream>>>(
      xb, wqb, b_qkv, (void*)qkv, MROWS, NQKV, DIMD);
  // 2) causal flash attention
  attn_fused<<<dim3(BB * NH * 8), dim3(512), 0, stream>>>(qkv, ctx);
  // 3) output projection — 128x128 GEMM (grid 512)
  gemm_bt_bias<true><<<dim3((MROWS / 128) * (DIMD / 128)), dim3(256), 0, stream>>>(
      ctx, wob, b_out, (void*)out, MROWS, DIMD, DIMD);
}

// Round 13
// 176.795 us; speedup vs baseline: 2.9013x; 1.0358x over previous
//
#include <hip/hip_runtime.h>

typedef unsigned short ushort_t;
typedef __bf16 bf16x8 __attribute__((ext_vector_type(8)));
typedef float f32x4 __attribute__((ext_vector_type(4)));

#define BB 4
#define TT 2048
#define DIMD 1024
#define NH 16
#define DK 64
#define MROWS (BB * TT)   /* 8192 */
#define NQKV (3 * DIMD)   /* 3072 */

__device__ __forceinline__ ushort_t f2b(float f) {
  __bf16 h = (__bf16)f;
  union { __bf16 h; ushort_t u; } c; c.h = h; return c.u;
}
__device__ __forceinline__ float fexp2(float x) {   // v_exp_f32: 2^x
  float r;
  asm("v_exp_f32 %0, %1" : "=v"(r) : "v"(x));
  return r;
}

// async global->LDS, 16B per lane; LDS dest is wave-uniform base + lane*16
__device__ __forceinline__ void gload_lds16(const void* g, void* l) {
  __builtin_amdgcn_global_load_lds(
      (const __attribute__((address_space(1))) void*)g,
      (__attribute__((address_space(3))) void*)l,
      16, 0, 0);
}

// f32 -> bf16 downcast, 8 elems/thread (n % 2048 == 0)
__global__ __launch_bounds__(256) void cast_f32_bf16(
    const float* __restrict__ in, ushort_t* __restrict__ out, int n)
{
  const int i = (blockIdx.x * 256 + threadIdx.x) * 8;
  if (i >= n) return;
  float4 a = *(const float4*)(in + i);
  float4 b = *(const float4*)(in + i + 4);
  ushort_t o[8];
  o[0] = f2b(a.x); o[1] = f2b(a.y); o[2] = f2b(a.z); o[3] = f2b(a.w);
  o[4] = f2b(b.x); o[5] = f2b(b.y); o[6] = f2b(b.z); o[7] = f2b(b.w);
  *(uint4*)(out + i) = *(const uint4*)o;
}

// ---------------- GEMM 128x256: 8-wave, triple-buffer, 1 barrier/K-tile -----
// C[m,n] = sum_k A[m,k]*W[n,k] + bias[n]. M%128==0, N%256==0, K%32==0.
// Per K-tile t (slot t%3):
//   vmcnt(3)  -> tile t in LDS (tile t+1's 3 loads stay in flight)
//   s_barrier -> all waves' tile-t DMA drained; slot (t+2)%3's readers done
//   ds_read 6xb128 ; issue stage(t+2) -> slot (t+2)%3 (WAR-free, no 2nd barrier)
//   lgkm0 ; 8 MFMA ; ds_read 2xb128 ; lgkm0 ; 8 MFMA
template <bool OUT_F32>
__global__ __launch_bounds__(512, 4) void gemm_bt_pipe(
    const ushort_t* __restrict__ A, const ushort_t* __restrict__ W,
    const float* __restrict__ bias, void* __restrict__ Cp,
    int M, int N, int K)
{
  __shared__ __align__(16) ushort_t As[3][128 * 32];
  __shared__ __align__(16) ushort_t Bs[3][256 * 32];

  const int tid = threadIdx.x;
  const int wave = tid >> 6, lane = tid & 63;
  const int tiles_n = N >> 8;
  const int nwg = (M >> 7) * tiles_n;
  int bid = blockIdx.x;
  { const int q = nwg >> 3; bid = (bid & 7) * q + (bid >> 3); }   // XCD swizzle (nwg%8==0)
  const int bm = bid / tiles_n, bn = bid % tiles_n;
  const int row0 = bm << 7, col0 = bn << 8;
  const int wm = (wave >> 2) << 6;   // 0 / 64
  const int wn = (wave & 3) << 6;    // 0,64,128,192
  const int fr = lane & 15;
  const int g  = lane >> 4;
  const int g4 = g << 2;
  const int csw = (g ^ (fr >> 2)) << 3;   // fragment-read chunk swizzle (elems)

  // staging: wave w covers 16 consecutive rows; lane -> row w*16+(lane>>2),
  // source chunk pre-XOR so linear LDS dest == swizzled layout
  const int srow = lane >> 2;
  const int scol = ((lane & 3) ^ ((lane >> 4) & 3)) << 3;
  const int lbase = wave << 9;            // wave-uniform LDS elem base

  const ushort_t* Ag  = A + (size_t)(row0 + (wave << 4) + srow) * K + scol;
  const ushort_t* Wg0 = W + (size_t)(col0 + (wave << 4) + srow) * K + scol;
  const ushort_t* Wg1 = Wg0 + (size_t)128 * K;

#define STAGE_P(kt, buf)                                                      \
  {                                                                           \
    const size_t _k = (size_t)(kt) << 5;                                      \
    gload_lds16(Ag + _k,  &As[buf][lbase]);                                   \
    gload_lds16(Wg0 + _k, &Bs[buf][lbase]);                                   \
    gload_lds16(Wg1 + _k, &Bs[buf][4096 + lbase]);                            \
  }

  const int NT = K >> 5;
  STAGE_P(0, 0);
  STAGE_P(1, 1);

  f32x4 acc[4][4] = {};
  int cr = 0, st = 2;

  for (int t = 0; t < NT; ++t) {
    if (t + 1 < NT) asm volatile("s_waitcnt vmcnt(3)" ::: "memory");
    else            asm volatile("s_waitcnt vmcnt(0)" ::: "memory");
    __builtin_amdgcn_s_barrier();

    const ushort_t* as_ = As[cr];
    const ushort_t* bs_ = Bs[cr];
    bf16x8 af0 = *(const bf16x8*)&as_[(wm +      fr) * 32 + csw];
    bf16x8 af1 = *(const bf16x8*)&as_[(wm + 16 + fr) * 32 + csw];
    bf16x8 bw0 = *(const bf16x8*)&bs_[(wn +      fr) * 32 + csw];
    bf16x8 bw1 = *(const bf16x8*)&bs_[(wn + 16 + fr) * 32 + csw];
    bf16x8 bw2 = *(const bf16x8*)&bs_[(wn + 32 + fr) * 32 + csw];
    bf16x8 bw3 = *(const bf16x8*)&bs_[(wn + 48 + fr) * 32 + csw];
    if (t + 2 < NT) STAGE_P(t + 2, st);
    asm volatile("s_waitcnt lgkmcnt(0)" ::: "memory");
    __builtin_amdgcn_sched_barrier(0);
    __builtin_amdgcn_s_setprio(1);
    acc[0][0] = __builtin_amdgcn_mfma_f32_16x16x32_bf16(af0, bw0, acc[0][0], 0, 0, 0);
    acc[0][1] = __builtin_amdgcn_mfma_f32_16x16x32_bf16(af0, bw1, acc[0][1], 0, 0, 0);
    acc[0][2] = __builtin_amdgcn_mfma_f32_16x16x32_bf16(af0, bw2, acc[0][2], 0, 0, 0);
    acc[0][3] = __builtin_amdgcn_mfma_f32_16x16x32_bf16(af0, bw3, acc[0][3], 0, 0, 0);
    acc[1][0] = __builtin_amdgcn_mfma_f32_16x16x32_bf16(af1, bw0, acc[1][0], 0, 0, 0);
    acc[1][1] = __builtin_amdgcn_mfma_f32_16x16x32_bf16(af1, bw1, acc[1][1], 0, 0, 0);
    acc[1][2] = __builtin_amdgcn_mfma_f32_16x16x32_bf16(af1, bw2, acc[1][2], 0, 0, 0);
    acc[1][3] = __builtin_amdgcn_mfma_f32_16x16x32_bf16(af1, bw3, acc[1][3], 0, 0, 0);
    __builtin_amdgcn_s_setprio(0);

    bf16x8 af2 = *(const bf16x8*)&as_[(wm + 32 + fr) * 32 + csw];
    bf16x8 af3 = *(const bf16x8*)&as_[(wm + 48 + fr) * 32 + csw];
    asm volatile("s_waitcnt lgkmcnt(0)" ::: "memory");
    __builtin_amdgcn_sched_barrier(0);
    __builtin_amdgcn_s_setprio(1);
    acc[2][0] = __builtin_amdgcn_mfma_f32_16x16x32_bf16(af2, bw0, acc[2][0], 0, 0, 0);
    acc[2][1] = __builtin_amdgcn_mfma_f32_16x16x32_bf16(af2, bw1, acc[2][1], 0, 0, 0);
    acc[2][2] = __builtin_amdgcn_mfma_f32_16x16x32_bf16(af2, bw2, acc[2][2], 0, 0, 0);
    acc[2][3] = __builtin_amdgcn_mfma_f32_16x16x32_bf16(af2, bw3, acc[2][3], 0, 0, 0);
    acc[3][0] = __builtin_amdgcn_mfma_f32_16x16x32_bf16(af3, bw0, acc[3][0], 0, 0, 0);
    acc[3][1] = __builtin_amdgcn_mfma_f32_16x16x32_bf16(af3, bw1, acc[3][1], 0, 0, 0);
    acc[3][2] = __builtin_amdgcn_mfma_f32_16x16x32_bf16(af3, bw2, acc[3][2], 0, 0, 0);
    acc[3][3] = __builtin_amdgcn_mfma_f32_16x16x32_bf16(af3, bw3, acc[3][3], 0, 0, 0);
    __builtin_amdgcn_s_setprio(0);

    ++cr; if (cr == 3) cr = 0;
    ++st; if (st == 3) st = 0;
  }
#undef STAGE_P

#pragma unroll
  for (int j = 0; j < 4; ++j) {
    const int col = col0 + wn + (j << 4) + fr;
    const float bv = bias[col];
#pragma unroll
    for (int i = 0; i < 4; ++i)
#pragma unroll
      for (int r = 0; r < 4; ++r) {
        const size_t row = (size_t)(row0 + wm + (i << 4) + g4 + r);
        if constexpr (OUT_F32)
          ((float*)Cp)[row * (size_t)N + col] = acc[i][j][r] + bv;
        else
          ((ushort_t*)Cp)[row * (size_t)N + col] = f2b(acc[i][j][r] + bv);
      }
  }
}

// ---------------- Flash attention (byte-identical to round 12) --------------
#define C1 0.18033688011112042f   /* 0.125 * log2(e) */
__global__ __launch_bounds__(512, 4) void attn_fused(
    const ushort_t* __restrict__ qkv, ushort_t* __restrict__ ctx)
{
  __shared__ __align__(16) ushort_t Qs[128 * 64];
  __shared__ __align__(16) ushort_t Ks[2][64 * 64];
  __shared__ __align__(16) ushort_t Vt[64 * 64];
  __shared__ __align__(16) ushort_t Ps[8][16 * 64];

  const int tid = threadIdx.x, wave = tid >> 6, lane = tid & 63;
  const int fr = lane & 15;
  const int g  = lane >> 4;
  const int fk = g << 3;
  const int g4 = g << 2;

  const int bid = blockIdx.x;
  const int bq  = (bid >> 3) & 7;
  const int G   = (bid & 7) | ((bid >> 6) << 3);
  const int h   = G & 15;
  const int b   = G >> 4;

  const int srl = lane >> 3;
  const int scc = ((lane & 7) ^ srl) << 3;
  const int vr  = tid >> 3;
  const int vc  = (tid & 7) << 3;
  const int rsw = (fr & 7) << 3;

  const ushort_t* Kg = qkv + (size_t)b * TT * NQKV + DIMD + h * DK;
  const ushort_t* Vg = qkv + (size_t)b * TT * NQKV + 2 * DIMD + h * DK;

#pragma unroll 1
  for (int t = 0; t < 2; ++t) {
    const int qt = t ? (15 - bq) : bq;
    const int ktmax = 2 * qt + 1;
    const int diag  = 2 * qt + (wave >> 2);
    const size_t qrow0 = (size_t)b * TT + (size_t)qt * 128;

    __syncthreads();

    const ushort_t* Qg = qkv + qrow0 * NQKV + h * DK;
#pragma unroll
    for (int pp = 0; pp < 2; ++pp) {
      const int e  = (wave << 9) + (pp << 12);
      const int rr = (e >> 6) + srl;
      gload_lds16(Qg + (size_t)rr * NQKV + scc, Qs + e);
    }
    {
      const int e  = wave << 9;
      const int rr = (wave << 3) + srl;
      gload_lds16(Kg + (size_t)rr * NQKV + scc, Ks[0] + e);
    }
    uint4 va = *(const uint4*)(Vg + (size_t)vr * NQKV + vc);
    asm volatile("s_waitcnt vmcnt(0)" ::: "memory");
    __syncthreads();

    bf16x8 aqr[2];
#pragma unroll
    for (int ks = 0; ks < 2; ++ks)
      aqr[ks] = *(const bf16x8*)&Qs[((wave << 4) + fr) * 64 + (((ks << 5) + fk) ^ rsw)];

    const int qrow = (qt << 7) + (wave << 4) + fr;
    float mrow = -1e30f, lrow = 0.f;
    f32x4 oacc[4] = {};
    int cur = 0;

    for (int kt = 0; kt <= ktmax; ++kt) {
      {
        __align__(16) ushort_t tmp[8];
        *(uint4*)tmp = va;
#pragma unroll
        for (int j = 0; j < 8; ++j) {
          const int d  = vc + j;
          const int hh = (d & 7) ^ ((d >> 3) & 7);
          Vt[d * 64 + (vr ^ (hh << 3))] = tmp[j];
        }
      }
      if (kt < ktmax) {
        const size_t krow = (size_t)(kt + 1) << 6;
        const int e  = wave << 9;
        const int rr = (wave << 3) + srl;
        gload_lds16(Kg + (krow + rr) * NQKV + scc, Ks[cur ^ 1] + e);
        va = *(const uint4*)(Vg + (krow + vr) * NQKV + vc);
      }
      asm volatile("s_waitcnt lgkmcnt(0)" ::: "memory");
      __builtin_amdgcn_s_barrier();

      if (kt <= diag) {
        f32x4 s[4] = {};
        __builtin_amdgcn_s_setprio(1);
#pragma unroll
        for (int ks = 0; ks < 2; ++ks)
#pragma unroll
          for (int ni = 0; ni < 4; ++ni) {
            const bf16x8 bk = *(const bf16x8*)&Ks[cur][((ni << 4) + fr) * 64 + (((ks << 5) + fk) ^ rsw)];
            s[ni] = __builtin_amdgcn_mfma_f32_16x16x32_bf16(bk, aqr[ks], s[ni], 0, 0, 0);
          }
        __builtin_amdgcn_s_setprio(0);

        if (kt == diag) {
          const int kb = kt << 6;
#pragma unroll
          for (int ni = 0; ni < 4; ++ni)
#pragma unroll
            for (int r = 0; r < 4; ++r) {
              const int kc = kb + (ni << 4) + g4 + r;
              if (kc > qrow) s[ni][r] = -1e30f;
            }
        }

        float rm = -1e30f;
#pragma unroll
        for (int ni = 0; ni < 4; ++ni) {
          const float m01 = fmaxf(s[ni][0], s[ni][1]);
          const float m23 = fmaxf(s[ni][2], s[ni][3]);
          rm = fmaxf(rm, fmaxf(m01, m23));
        }
        rm = fmaxf(rm, __shfl_xor(rm, 16, 64));
        rm = fmaxf(rm, __shfl_xor(rm, 32, 64));

        if (__any(rm > mrow + 64.f)) {
          const float mn = fmaxf(mrow, rm);
          const float corr = fexp2((mrow - mn) * C1);
          mrow = mn;
          lrow *= corr;
#pragma unroll
          for (int ni = 0; ni < 4; ++ni) oacc[ni] *= corr;
        }
        const float nm2 = -mrow * C1;
        float rs = 0.f;
#pragma unroll
        for (int ni = 0; ni < 4; ++ni)
#pragma unroll
          for (int r = 0; r < 4; ++r) {
            const float pe = fexp2(fmaf(s[ni][r], C1, nm2));
            s[ni][r] = pe;
            rs += pe;
          }
        rs += __shfl_xor(rs, 16, 64);
        rs += __shfl_xor(rs, 32, 64);
        lrow += rs;

#pragma unroll
        for (int ni = 0; ni < 4; ++ni) {
          ushort_t o4[4];
#pragma unroll
          for (int r = 0; r < 4; ++r) o4[r] = f2b(s[ni][r]);
          *(uint2*)&Ps[wave][fr * 64 + (((ni << 4) + g4) ^ rsw)] = *(const uint2*)o4;
        }
        asm volatile("s_waitcnt lgkmcnt(0)" ::: "memory");
        __builtin_amdgcn_sched_barrier(0);

        __builtin_amdgcn_s_setprio(1);
#pragma unroll
        for (int ks = 0; ks < 2; ++ks) {
          const bf16x8 ap = *(const bf16x8*)&Ps[wave][fr * 64 + (((ks << 5) + fk) ^ rsw)];
#pragma unroll
          for (int ni = 0; ni < 4; ++ni) {
            const int hh = (fr & 7) ^ ((2 * ni + (fr >> 3)) & 7);
            const bf16x8 bv = *(const bf16x8*)&Vt[((ni << 4) + fr) * 64 + (((ks << 5) + fk) ^ (hh << 3))];
            oacc[ni] = __builtin_amdgcn_mfma_f32_16x16x32_bf16(bv, ap, oacc[ni], 0, 0, 0);
          }
        }
        __builtin_amdgcn_s_setprio(0);
      }

      if (kt < ktmax) {
        asm volatile("s_waitcnt vmcnt(0)" ::: "memory");
        __syncthreads();
      }
      cur ^= 1;
    }

    const float inv = 1.f / lrow;
    ushort_t* crow = ctx + (qrow0 + (wave << 4) + fr) * DIMD + h * DK;
#pragma unroll
    for (int ni = 0; ni < 4; ++ni) {
      ushort_t o4[4];
#pragma unroll
      for (int r = 0; r < 4; ++r) o4[r] = f2b(oacc[ni][r] * inv);
      *(uint2*)&crow[(ni << 4) + g4] = *(const uint2*)o4;
    }
  }
}

extern "C" void kernel_launch(void* const* d_in, const int* in_sizes, int n_in,
                              void* d_out, int out_size, void* d_ws, size_t ws_size,
                              hipStream_t stream) {
  const float* x     = (const float*)d_in[0];
  const float* w_qkv = (const float*)d_in[1];
  const float* b_qkv = (const float*)d_in[2];
  const float* w_out = (const float*)d_in[3];
  const float* b_out = (const float*)d_in[4];

  const size_t need = 36u * 1024 * 1024 * sizeof(ushort_t);   // 72 MiB
  if (ws_size < need) return;

  ushort_t* qkv = (ushort_t*)d_ws;
  ushort_t* xb  = qkv + (size_t)MROWS * NQKV;
  ushort_t* wqb = xb  + (size_t)MROWS * DIMD;
  ushort_t* wob = wqb + (size_t)NQKV * DIMD;
  ushort_t* ctx = xb;
  float*    out = (float*)d_out;

  cast_f32_bf16<<<dim3(MROWS * DIMD / 2048), dim3(256), 0, stream>>>(x, xb, MROWS * DIMD);
  cast_f32_bf16<<<dim3(NQKV * DIMD / 2048), dim3(256), 0, stream>>>(w_qkv, wqb, NQKV * DIMD);
  cast_f32_bf16<<<dim3(DIMD * DIMD / 2048), dim3(256), 0, stream>>>(w_out, wob, DIMD * DIMD);
  // 1) QKV projection — 128x256 triple-buffer pipeline (grid 768, 512 thr)
  gemm_bt_pipe<false><<<dim3((MROWS / 128) * (NQKV / 256)), dim3(512), 0, stream>>>(
      xb, wqb, b_qkv, (void*)qkv, MROWS, NQKV, DIMD);
  // 2) causal flash attention
  attn_fused<<<dim3(BB * NH * 8), dim3(512), 0, stream>>>(qkv, ctx);
  // 3) output projection — same pipeline (grid 256)
  gemm_bt_pipe<true><<<dim3((MROWS / 128) * (DIMD / 256)), dim3(512), 0, stream>>>(
      ctx, wob, b_out, (void*)out, MROWS, DIMD, DIMD);
}